// Round 16
// baseline (192.879 us; speedup 1.0000x reference)
//
#include <hip/hip_runtime.h>
#include <cstddef>
#include <cstdint>

// Problem constants (B,N,H) = (8,256,64)
constexpr int Bv = 8, Nv = 256, Hv = 64;
constexpr int ROWS = Bv * Nv;            // 2048
constexpr int EBLK = 512;                // edge kernels: 4 bi per block
constexpr float INV_EDGE_CNT = 1.0f / (8.0f * 256.0f * 256.0f);
constexpr float INV_NODE_CNT = 1.0f / 2048.0f;
constexpr float EPSBN = 1e-5f;

// ws layout (float offsets)
constexpr size_t WS_VXE  = 0;          // [2048*64] PACKED [b][jt][t][lane][4]
constexpr size_t WS_VXN  = 131072;     // [2048*64] PACKED
constexpr size_t WS_UX   = 262144;     // [2048*64] linear [r][c]
constexpr size_t WS_AGG  = 393216;     // [2048*64] linear [r][c]
constexpr size_t WS_ESUM = 524288;     // [64]  k_node writes edge-BN scale
constexpr size_t WS_ESQ  = 524352;     // [64]  k_node writes edge-BN shift
constexpr size_t WS_PART = 524416;     // [512][128] per-block partial s|q

typedef __bf16 bf16x8 __attribute__((ext_vector_type(8)));
typedef float  f32x4  __attribute__((ext_vector_type(4)));

__device__ __forceinline__ float4 ld4(const float* p) {
  return *reinterpret_cast<const float4*>(p);
}

__device__ __forceinline__ bf16x8 cvt8(float4 a, float4 b) {
  bf16x8 r;
  r[0] = (__bf16)a.x; r[1] = (__bf16)a.y; r[2] = (__bf16)a.z; r[3] = (__bf16)a.w;
  r[4] = (__bf16)b.x; r[5] = (__bf16)b.y; r[6] = (__bf16)b.z; r[7] = (__bf16)b.w;
  return r;
}

// A-fragment (one 16-j MFMA tile) direct global->regs; per-lane private.
__device__ __forceinline__ void loadA(float4 A[4], const float* eTile,
                                      int j0, int r16, int g) {
  const float* ep = eTile + (size_t)(j0 + r16) * 64 + 8 * g;
  A[0] = ld4(ep);      A[1] = ld4(ep + 4);
  A[2] = ld4(ep + 32); A[3] = ld4(ep + 36);
}

// edgeC helpers (r8/r14): global tile -> regs (chunk-swizzled source),
// then linear LDS write-back.
__device__ __forceinline__ void load_tile_G(const float* eTile, int w, int lane,
                                            int tt, float4 G[4]) {
#pragma unroll
  for (int k = 0; k < 4; ++k) {
    const int m  = k * 64 + lane;
    const int rl = m >> 4;
    const int pp = m & 15;
    const int cc = pp ^ (rl & 7);
    G[k] = ld4(eTile + (size_t)(w * 64 + tt * 16 + rl) * 64 + cc * 4);
  }
}

__device__ __forceinline__ void write_tile_L(float* myBuf, int lane, int s,
                                             const float4 G[4]) {
#pragma unroll
  for (int k = 0; k < 4; ++k)
    *(float4*)(myBuf + s * 1024 + k * 256 + lane * 4) = G[k];
}

#define DOT4(acc, a, b) \
  acc = fmaf((a).x, (b).x, fmaf((a).y, (b).y, fmaf((a).z, (b).z, fmaf((a).w, (b).w, acc))))

// ---------------------------------------------------------------------------
// Linears (r14): Vxe / Vxn PACKED f32; Ux linear. 256 blocks x 128 threads.
__global__ __launch_bounds__(128) void k_lin(
    const float* __restrict__ x,
    const float* __restrict__ VeW, const float* __restrict__ Veb,
    const float* __restrict__ UnW, const float* __restrict__ Unb,
    const float* __restrict__ VnW, const float* __restrict__ Vnb,
    float* __restrict__ ws)
{
  const int idx = blockIdx.x * 128 + threadIdx.x;   // 32768 total
  const int r  = idx >> 4;           // row 0..2047
  const int tg = idx & 15;
  const int t  = tg >> 2, g = tg & 3;
  const int c0 = t * 16 + g * 4;

  const float4* x4 = (const float4*)(x + (size_t)r * 64);
  float a1[4] = {}, a2[4] = {}, a3[4] = {};
#pragma unroll
  for (int h = 0; h < 16; ++h) {
    float4 xv = x4[h];
#pragma unroll
    for (int cc = 0; cc < 4; ++cc) {
      float4 w1 = ld4(VeW + (size_t)(c0 + cc) * 64 + h * 4); DOT4(a1[cc], xv, w1);
      float4 w2 = ld4(UnW + (size_t)(c0 + cc) * 64 + h * 4); DOT4(a2[cc], xv, w2);
      float4 w3 = ld4(VnW + (size_t)(c0 + cc) * 64 + h * 4); DOT4(a3[cc], xv, w3);
    }
  }

  const int b = r >> 8, jt = (r >> 4) & 15, r16 = r & 15;
  const size_t pidx = ((size_t)((b * 16 + jt) * 4 + t)) * 256 + (g * 16 + r16) * 4;
  *(float4*)(&ws[WS_VXE + pidx]) =
      make_float4(a1[0] + Veb[c0], a1[1] + Veb[c0 + 1], a1[2] + Veb[c0 + 2], a1[3] + Veb[c0 + 3]);
  *(float4*)(&ws[WS_VXN + pidx]) =
      make_float4(a3[0] + Vnb[c0], a3[1] + Vnb[c0 + 1], a3[2] + Vnb[c0 + 2], a3[3] + Vnb[c0 + 3]);
  *(float4*)(&ws[WS_UX + (size_t)r * 64 + c0]) =
      make_float4(a2[0] + Unb[c0], a2[1] + Unb[c0 + 1], a2[2] + Unb[c0 + 2], a2[3] + Unb[c0 + 3]);
}

// ---------------------------------------------------------------------------
// Pass A, 4-bi blocks: 512 blocks; each runs the proven r14 edgeA body for
// bi = 4*bid..+3 (same batch b -> W/vj/vn panels L1/L2-hot across q; W frags
// loaded once). Stats accumulate across all 4 bi -> ONE partial row/block.
__global__ __launch_bounds__(256, 2) void k_edgeA4(
    const float* __restrict__ e,
    const float* __restrict__ UeW, const float* __restrict__ Ueb,
    float* __restrict__ ws)
{
  __shared__ float redL[3 * 256];

  const int tid  = threadIdx.x;
  const int lane = tid & 63;
  const int w    = tid >> 6;
  const int bi0  = blockIdx.x * 4;
  const int b    = bi0 >> 8;          // constant across q (bi0 % 256 <= 252)
  const int r16  = lane & 15;
  const int g    = lane >> 4;

  const float* VXEP = ws + WS_VXE;
  const float* VXNP = ws + WS_VXN;

  // W fragments once per block
  bf16x8 wF0[4], wF1[4];
#pragma unroll
  for (int t = 0; t < 4; ++t) {
    const float* wrow = UeW + (size_t)(t * 16 + r16) * 64 + 8 * g;
    wF0[t] = cvt8(ld4(wrow),      ld4(wrow + 4));
    wF1[t] = cvt8(ld4(wrow + 32), ld4(wrow + 36));
  }

  float4 ueb4[4];
#pragma unroll
  for (int t = 0; t < 4; ++t) ueb4[t] = ld4(Ueb + t * 16 + 4 * g);

  float sSg[4][4] = {}, sQg[4][4] = {};

#pragma unroll
  for (int q = 0; q < 4; ++q) {
    const int bi = bi0 + q;
    const float* eTile = e + (size_t)bi * (Nv * Hv);

    // uv = Ueb + Vxe_i for this bi
    const int jti = (bi >> 4) & 15, r16i = bi & 15;
    float uv[4][4];
#pragma unroll
    for (int t = 0; t < 4; ++t) {
      float4 vi = ld4(VXEP + ((size_t)((b * 16 + jti) * 4 + t)) * 256 + (g * 16 + r16i) * 4);
      uv[t][0] = ueb4[t].x + vi.x; uv[t][1] = ueb4[t].y + vi.y;
      uv[t][2] = ueb4[t].z + vi.z; uv[t][3] = ueb4[t].w + vi.w;
    }

    float4 A0[4], A1[4];
    loadA(A0, eTile, w * 64 + 0 * 16, r16, g);
    loadA(A1, eTile, w * 64 + 1 * 16, r16, g);

    float sA[4][4] = {};

#pragma unroll
    for (int p = 0; p < 4; ++p) {
      const size_t pb = (size_t)((b * 16 + (w * 4 + p)) * 4);
      float4 vj4[4], vn4[4];
#pragma unroll
      for (int t = 0; t < 4; ++t) {
        vj4[t] = ld4(VXEP + (pb + t) * 256 + lane * 4);
        vn4[t] = ld4(VXNP + (pb + t) * 256 + lane * 4);
      }

      float4* As = (p & 1) ? A1 : A0;
      bf16x8 aF0 = cvt8(As[0], As[1]);
      bf16x8 aF1 = cvt8(As[2], As[3]);
      if (p < 2) loadA(As, eTile, w * 64 + (p + 2) * 16, r16, g);

      f32x4 acc[4];
#pragma unroll
      for (int t = 0; t < 4; ++t) {
        f32x4 z = {0.f, 0.f, 0.f, 0.f};
        acc[t] = __builtin_amdgcn_mfma_f32_16x16x32_bf16(wF0[t], aF0, z, 0, 0, 0);
        acc[t] = __builtin_amdgcn_mfma_f32_16x16x32_bf16(wF1[t], aF1, acc[t], 0, 0, 0);
      }

#pragma unroll
      for (int t = 0; t < 4; ++t) {
        float vj[4] = {vj4[t].x, vj4[t].y, vj4[t].z, vj4[t].w};
        float vn[4] = {vn4[t].x, vn4[t].y, vn4[t].z, vn4[t].w};
#pragma unroll
        for (int r = 0; r < 4; ++r) {
          float tv = acc[t][r] + uv[t][r] + vj[r];
          sSg[t][r] += tv;
          sQg[t][r]  = fmaf(tv, tv, sQg[t][r]);
          float sg   = __builtin_amdgcn_rcpf(1.0f + __expf(-tv));
          sA[t][r]   = fmaf(sg, vn[r], sA[t][r]);
        }
      }
    }

    // agg: reduce sA over the 16 j-lanes, cross-wave via redL
#pragma unroll
    for (int t = 0; t < 4; ++t)
#pragma unroll
      for (int r = 0; r < 4; ++r) {
#pragma unroll
        for (int m = 1; m < 16; m <<= 1)
          sA[t][r] += __shfl_xor(sA[t][r], m);
      }
    if (r16 == 0) {
#pragma unroll
      for (int t = 0; t < 4; ++t)
        *(float4*)(&redL[w * 64 + t * 16 + 4 * g]) =
            make_float4(sA[t][0], sA[t][1], sA[t][2], sA[t][3]);
    }
    __syncthreads();
    if (tid < 64) {
      const int c = tid;
      ws[WS_AGG + (size_t)bi * 64 + c] =
          redL[c] + redL[64 + c] + redL[128 + c] + redL[192 + c];
    }
    __syncthreads();
  }

  // stats: reduce over 16 j-lanes, cross-wave, ONE partial row per block
#pragma unroll
  for (int t = 0; t < 4; ++t)
#pragma unroll
    for (int r = 0; r < 4; ++r) {
#pragma unroll
      for (int m = 1; m < 16; m <<= 1) {
        sSg[t][r] += __shfl_xor(sSg[t][r], m);
        sQg[t][r] += __shfl_xor(sQg[t][r], m);
      }
    }
  if (r16 == 0) {
#pragma unroll
    for (int t = 0; t < 4; ++t) {
      const int cb = w * 64 + t * 16 + 4 * g;
      *(float4*)(&redL[cb])       = make_float4(sSg[t][0], sSg[t][1], sSg[t][2], sSg[t][3]);
      *(float4*)(&redL[256 + cb]) = make_float4(sQg[t][0], sQg[t][1], sQg[t][2], sQg[t][3]);
    }
  }
  __syncthreads();
  if (tid < 64) {
    const int c = tid;
    ws[WS_PART + (size_t)blockIdx.x * 128 + c] =
        redL[c] + redL[64 + c] + redL[128 + c] + redL[192 + c];
    ws[WS_PART + (size_t)blockIdx.x * 128 + 64 + c] =
        redL[256 + c] + redL[256 + 64 + c] + redL[256 + 128 + c] + redL[256 + 192 + c];
  }
}

// ---------------------------------------------------------------------------
// Node path: fold 512 edge partials -> edge-BN scale/shift; then node BN.
__global__ __launch_bounds__(256) void k_node(
    const float* __restrict__ x,
    const float* __restrict__ bnng, const float* __restrict__ bnnb,
    const float* __restrict__ bneg, const float* __restrict__ bneb,
    float* __restrict__ ws, float* __restrict__ xOut)
{
  const int c = blockIdx.x;
  const int tid = threadIdx.x;
  __shared__ float ss[4], qq[4];
  const int w = tid >> 6;

  float S = 0.f, Q = 0.f;
#pragma unroll
  for (int k = 0; k < 2; ++k) {
    const size_t row = (size_t)(tid + 256 * k) * 128;
    S += ws[WS_PART + row + c];
    Q += ws[WS_PART + row + 64 + c];
  }
#pragma unroll
  for (int m = 1; m < 64; m <<= 1) {
    S += __shfl_xor(S, m);
    Q += __shfl_xor(Q, m);
  }
  if ((tid & 63) == 0) { ss[w] = S; qq[w] = Q; }
  __syncthreads();
  if (tid == 0) {
    float Se = ss[0] + ss[1] + ss[2] + ss[3];
    float Qe = qq[0] + qq[1] + qq[2] + qq[3];
    float mean = Se * INV_EDGE_CNT;
    float var  = Qe * INV_EDGE_CNT - mean * mean;
    float sc = rsqrtf(var + EPSBN) * bneg[c];
    ws[WS_ESUM + c] = sc;
    ws[WS_ESQ  + c] = bneb[c] - mean * sc;
  }
  __syncthreads();

  const float* Ux  = ws + WS_UX;
  const float* agg = ws + WS_AGG;

  float v[8];
  float s = 0.f, q = 0.f;
#pragma unroll
  for (int k = 0; k < 8; ++k) {
    int r = tid + 256 * k;
    float t = Ux[(size_t)r * 64 + c] + agg[(size_t)r * 64 + c];
    v[k] = t;
    s += t;
    q = fmaf(t, t, q);
  }
#pragma unroll
  for (int m = 1; m < 64; m <<= 1) {
    s += __shfl_xor(s, m);
    q += __shfl_xor(q, m);
  }
  if ((tid & 63) == 0) { ss[w] = s; qq[w] = q; }
  __syncthreads();
  float Sn = ss[0] + ss[1] + ss[2] + ss[3];
  float Qn = qq[0] + qq[1] + qq[2] + qq[3];
  float mean = Sn * INV_NODE_CNT;
  float var  = Qn * INV_NODE_CNT - mean * mean;
  float scv = rsqrtf(var + EPSBN) * bnng[c];
  float shv = bnnb[c] - mean * scv;
#pragma unroll
  for (int k = 0; k < 8; ++k) {
    int r = tid + 256 * k;
    float y = fmaf(v[k], scv, shv);
    xOut[(size_t)r * 64 + c] = fmaxf(y, 0.f) + x[(size_t)r * 64 + c];
  }
}

// ---------------------------------------------------------------------------
// Pass C, 4-bi blocks: W->LDS once + fragments hoisted to regs; per bi the
// r8/r14 register-staged LDS pipeline (residual from staged tile). eL regions
// are per-wave private -> no barriers inside/between bi iterations.
__global__ __launch_bounds__(256, 2) void k_edgeC4(
    const float* __restrict__ e,
    const float* __restrict__ UeW, const float* __restrict__ Ueb,
    const float* __restrict__ ws, float* __restrict__ eOut)
{
  __shared__ __align__(16) float eL[4 * 2048];     // 32KB
  __shared__ __align__(16) __bf16 wLds[4096];      // 8KB

  const int tid  = threadIdx.x;
  const int lane = tid & 63;
  const int w    = tid >> 6;
  const int bi0  = blockIdx.x * 4;
  const int b    = bi0 >> 8;
  const int r16  = lane & 15;
  const int g    = lane >> 4;
  const int sw   = r16 & 7;

  float* myBuf = &eL[w * 2048];
  const float* VXEP = ws + WS_VXE;

  // stage W -> LDS (chunk-swizzled), once per block
#pragma unroll
  for (int k = 0; k < 2; ++k) {
    const int m = tid * 2 + k;
    const int c = m >> 3, p = m & 7;
    float4 lo = ld4(UeW + (size_t)c * 64 + p * 8);
    float4 hi = ld4(UeW + (size_t)c * 64 + p * 8 + 4);
    *(bf16x8*)(&wLds[(size_t)c * 64 + (size_t)(p ^ (c & 7)) * 8]) = cvt8(lo, hi);
  }

  float4 ueb4[4], sc4[4], sh4[4];
#pragma unroll
  for (int t = 0; t < 4; ++t) {
    ueb4[t] = ld4(Ueb + t * 16 + 4 * g);
    sc4[t]  = ld4(ws + WS_ESUM + t * 16 + 4 * g);
    sh4[t]  = ld4(ws + WS_ESQ  + t * 16 + 4 * g);
  }

  __syncthreads();
  // W fragments once into regs
  bf16x8 wF0[4], wF1[4];
#pragma unroll
  for (int t = 0; t < 4; ++t) {
    const int wr = (16 * t + r16) * 64;
    wF0[t] = *(const bf16x8*)(&wLds[wr + ((g ^ sw) << 3)]);
    wF1[t] = *(const bf16x8*)(&wLds[wr + (((4 + g) ^ sw) << 3)]);
  }

#pragma unroll
  for (int q = 0; q < 4; ++q) {
    const int bi = bi0 + q;
    const float* eTile = e + (size_t)bi * (Nv * Hv);
    float* oTile = eOut + (size_t)bi * (Nv * Hv);

    const int jti = (bi >> 4) & 15, r16i = bi & 15;
    float4 vxei4[4];
#pragma unroll
    for (int t = 0; t < 4; ++t)
      vxei4[t] = ld4(VXEP + ((size_t)((b * 16 + jti) * 4 + t)) * 256 + (g * 16 + r16i) * 4);

    float4 Ga[4], Gb[4];
    float4 Pj[2][4];
    load_tile_G(eTile, w, lane, 0, Ga);
    load_tile_G(eTile, w, lane, 1, Gb);
    {
      const size_t pb0 = (size_t)((b * 16 + (w * 4 + 0)) * 4);
#pragma unroll
      for (int t = 0; t < 4; ++t)
        Pj[0][t] = ld4(VXEP + (pb0 + t) * 256 + lane * 4);
    }
    write_tile_L(myBuf, lane, 0, Ga);
    write_tile_L(myBuf, lane, 1, Gb);

#pragma unroll
    for (int p = 0; p < 4; ++p) {
      const float* rbase = myBuf + (p & 1) * 1024 + r16 * 64;
      float4 f0 = ld4(rbase + (((2 * g)     ^ sw) << 2));
      float4 f1 = ld4(rbase + (((2 * g + 1) ^ sw) << 2));
      float4 f2 = ld4(rbase + ((((2 * g)     ^ sw) + 8) << 2));
      float4 f3 = ld4(rbase + ((((2 * g + 1) ^ sw) + 8) << 2));
      bf16x8 aF0 = cvt8(f0, f1);
      bf16x8 aF1 = cvt8(f2, f3);
      float4 res4[4];
#pragma unroll
      for (int t = 0; t < 4; ++t)
        res4[t] = ld4(rbase + (((4 * t + g) ^ sw) << 2));

      if (p < 3) {
        const size_t pbn = (size_t)((b * 16 + (w * 4 + p + 1)) * 4);
#pragma unroll
        for (int t = 0; t < 4; ++t)
          Pj[(p + 1) & 1][t] = ld4(VXEP + (pbn + t) * 256 + lane * 4);
      }
      if (p < 2) load_tile_G(eTile, w, lane, p + 2, (p & 1) ? Gb : Ga);

      f32x4 acc[4];
#pragma unroll
      for (int t = 0; t < 4; ++t) {
        f32x4 z = {0.f, 0.f, 0.f, 0.f};
        acc[t] = __builtin_amdgcn_mfma_f32_16x16x32_bf16(wF0[t], aF0, z, 0, 0, 0);
        acc[t] = __builtin_amdgcn_mfma_f32_16x16x32_bf16(wF1[t], aF1, acc[t], 0, 0, 0);
      }

      const int j = w * 64 + p * 16 + r16;
#pragma unroll
      for (int t = 0; t < 4; ++t) {
        float vj[4] = {Pj[p & 1][t].x, Pj[p & 1][t].y, Pj[p & 1][t].z, Pj[p & 1][t].w};
        float rs[4] = {res4[t].x, res4[t].y, res4[t].z, res4[t].w};
        float ub[4] = {ueb4[t].x, ueb4[t].y, ueb4[t].z, ueb4[t].w};
        float vi[4] = {vxei4[t].x, vxei4[t].y, vxei4[t].z, vxei4[t].w};
        float sc[4] = {sc4[t].x, sc4[t].y, sc4[t].z, sc4[t].w};
        float sh[4] = {sh4[t].x, sh4[t].y, sh4[t].z, sh4[t].w};
        float out[4];
#pragma unroll
        for (int r = 0; r < 4; ++r) {
          float tv = acc[t][r] + ub[r] + vi[r] + vj[r];
          float y  = fmaf(tv, sc[r], sh[r]);
          out[r] = fmaxf(y, 0.f) + rs[r];
        }
        *(float4*)(oTile + (size_t)j * 64 + t * 16 + 4 * g) =
            make_float4(out[0], out[1], out[2], out[3]);
      }

      if (p < 2) write_tile_L(myBuf, lane, p & 1, (p & 1) ? Gb : Ga);
      __builtin_amdgcn_sched_barrier(0);
    }
  }
}

// ---------------------------------------------------------------------------
extern "C" void kernel_launch(void* const* d_in, const int* in_sizes, int n_in,
                              void* d_out, int out_size, void* d_ws, size_t ws_size,
                              hipStream_t stream)
{
  const float* x    = (const float*)d_in[0];
  const float* e    = (const float*)d_in[1];
  const float* UeW  = (const float*)d_in[2];
  const float* Ueb  = (const float*)d_in[3];
  const float* VeW  = (const float*)d_in[4];
  const float* Veb  = (const float*)d_in[5];
  const float* UnW  = (const float*)d_in[6];
  const float* Unb  = (const float*)d_in[7];
  const float* VnW  = (const float*)d_in[8];
  const float* Vnb  = (const float*)d_in[9];
  const float* bneg = (const float*)d_in[10];
  const float* bneb = (const float*)d_in[11];
  const float* bnng = (const float*)d_in[12];
  const float* bnnb = (const float*)d_in[13];

  float* ws   = (float*)d_ws;
  float* xOut = (float*)d_out;
  float* eOut = (float*)d_out + (size_t)ROWS * Hv;

  k_lin<<<256, 128, 0, stream>>>(x, VeW, Veb, UnW, Unb, VnW, Vnb, ws);
  k_edgeA4<<<EBLK, 256, 0, stream>>>(e, UeW, Ueb, ws);
  k_node<<<Hv, 256, 0, stream>>>(x, bnng, bnnb, bneg, bneb, ws, xOut);
  k_edgeC4<<<EBLK, 256, 0, stream>>>(e, UeW, Ueb, ws, eOut);
}

// Round 17
// 122.577 us; speedup vs baseline: 1.5735x; 1.5735x over previous
//
#include <hip/hip_runtime.h>
#include <cstddef>
#include <cstdint>

// Problem constants (B,N,H) = (8,256,64)
constexpr int Bv = 8, Nv = 256, Hv = 64;
constexpr int ROWS = Bv * Nv;            // 2048
constexpr float INV_EDGE_CNT = 1.0f / (8.0f * 256.0f * 256.0f);
constexpr float INV_NODE_CNT = 1.0f / 2048.0f;
constexpr float EPSBN = 1e-5f;

// ws layout (float offsets)
constexpr size_t WS_VXE  = 0;          // [2048*64] PACKED [b][jt][t][lane][4]
constexpr size_t WS_VXN  = 131072;     // [2048*64] PACKED
constexpr size_t WS_UX   = 262144;     // [2048*64] linear [r][c]
constexpr size_t WS_AGG  = 393216;     // [2048*64] linear [r][c]
constexpr size_t WS_ESUM = 524288;     // [64]  k_node writes edge-BN scale
constexpr size_t WS_ESQ  = 524352;     // [64]  k_node writes edge-BN shift
constexpr size_t WS_PART = 524416;     // [2048][128] per-block partial s|q

typedef __bf16 bf16x8 __attribute__((ext_vector_type(8)));
typedef float  f32x4  __attribute__((ext_vector_type(4)));

__device__ __forceinline__ float4 ld4(const float* p) {
  return *reinterpret_cast<const float4*>(p);
}

__device__ __forceinline__ bf16x8 cvt8(float4 a, float4 b) {
  bf16x8 r;
  r[0] = (__bf16)a.x; r[1] = (__bf16)a.y; r[2] = (__bf16)a.z; r[3] = (__bf16)a.w;
  r[4] = (__bf16)b.x; r[5] = (__bf16)b.y; r[6] = (__bf16)b.z; r[7] = (__bf16)b.w;
  return r;
}

// A-fragment (one 16-j MFMA tile) direct global->regs; per-lane private.
__device__ __forceinline__ void loadA(float4 A[4], const float* eTile,
                                      int j0, int r16, int g) {
  const float* ep = eTile + (size_t)(j0 + r16) * 64 + 8 * g;
  A[0] = ld4(ep);      A[1] = ld4(ep + 4);
  A[2] = ld4(ep + 32); A[3] = ld4(ep + 36);
}

// r8 edgeC helpers: global tile load into regs (chunk-swizzled source) and
// linear LDS write-back.
__device__ __forceinline__ void load_tile_G(const float* eTile, int w, int lane,
                                            int tt, float4 G[4]) {
#pragma unroll
  for (int k = 0; k < 4; ++k) {
    const int m  = k * 64 + lane;
    const int rl = m >> 4;
    const int pp = m & 15;
    const int cc = pp ^ (rl & 7);
    G[k] = ld4(eTile + (size_t)(w * 64 + tt * 16 + rl) * 64 + cc * 4);
  }
}

__device__ __forceinline__ void write_tile_L(float* myBuf, int lane, int s,
                                             const float4 G[4]) {
#pragma unroll
  for (int k = 0; k < 4; ++k)
    *(float4*)(myBuf + s * 1024 + k * 256 + lane * 4) = G[k];
}

#define DOT4(acc, a, b) \
  acc = fmaf((a).x, (b).x, fmaf((a).y, (b).y, fmaf((a).z, (b).z, fmaf((a).w, (b).w, acc))))

// ---------------------------------------------------------------------------
// Linears: Vxe / Vxn written PACKED f32 for the edge-kernel epilogue lane
// order; Ux linear. 256 blocks x 128 threads (full-GPU spread).
__global__ __launch_bounds__(128) void k_lin(
    const float* __restrict__ x,
    const float* __restrict__ VeW, const float* __restrict__ Veb,
    const float* __restrict__ UnW, const float* __restrict__ Unb,
    const float* __restrict__ VnW, const float* __restrict__ Vnb,
    float* __restrict__ ws)
{
  const int idx = blockIdx.x * 128 + threadIdx.x;   // 32768 total
  const int r  = idx >> 4;           // row 0..2047
  const int tg = idx & 15;
  const int t  = tg >> 2, g = tg & 3;
  const int c0 = t * 16 + g * 4;

  const float4* x4 = (const float4*)(x + (size_t)r * 64);
  float a1[4] = {}, a2[4] = {}, a3[4] = {};
#pragma unroll
  for (int h = 0; h < 16; ++h) {
    float4 xv = x4[h];
#pragma unroll
    for (int cc = 0; cc < 4; ++cc) {
      float4 w1 = ld4(VeW + (size_t)(c0 + cc) * 64 + h * 4); DOT4(a1[cc], xv, w1);
      float4 w2 = ld4(UnW + (size_t)(c0 + cc) * 64 + h * 4); DOT4(a2[cc], xv, w2);
      float4 w3 = ld4(VnW + (size_t)(c0 + cc) * 64 + h * 4); DOT4(a3[cc], xv, w3);
    }
  }

  const int b = r >> 8, jt = (r >> 4) & 15, r16 = r & 15;
  const size_t pidx = ((size_t)((b * 16 + jt) * 4 + t)) * 256 + (g * 16 + r16) * 4;
  *(float4*)(&ws[WS_VXE + pidx]) =
      make_float4(a1[0] + Veb[c0], a1[1] + Veb[c0 + 1], a1[2] + Veb[c0 + 2], a1[3] + Veb[c0 + 3]);
  *(float4*)(&ws[WS_VXN + pidx]) =
      make_float4(a3[0] + Vnb[c0], a3[1] + Vnb[c0 + 1], a3[2] + Vnb[c0 + 2], a3[3] + Vnb[c0 + 3]);
  *(float4*)(&ws[WS_UX + (size_t)r * 64 + c0]) =
      make_float4(a2[0] + Unb[c0], a2[1] + Unb[c0 + 1], a2[2] + Unb[c0 + 2], a2[3] + Unb[c0 + 3]);
}

// ---------------------------------------------------------------------------
// Pass A (r9/r14 — best measured): LDS-free, A-fragments per-lane private
// with 2-tile register prefetch; launch_bounds(256,3) caps the unified
// VGPR+AGPR allocation -> 3 waves/SIMD without spill; per-block partials.
__global__ __launch_bounds__(256, 3) void k_edgeA(
    const float* __restrict__ e,
    const float* __restrict__ UeW, const float* __restrict__ Ueb,
    float* __restrict__ ws)
{
  __shared__ float redL[3 * 256];    // 3KB: cross-wave reduce only

  const int tid  = threadIdx.x;
  const int lane = tid & 63;
  const int w    = tid >> 6;
  const int bi   = blockIdx.x;
  const int b    = bi >> 8;
  const int r16  = lane & 15;
  const int g    = lane >> 4;

  const float* eTile = e + (size_t)bi * (Nv * Hv);
  const float* VXEP = ws + WS_VXE;
  const float* VXNP = ws + WS_VXN;

  // W fragments (A-operand of mfma(W,e)) direct from global (L2-hot 16KB)
  bf16x8 wF0[4], wF1[4];
#pragma unroll
  for (int t = 0; t < 4; ++t) {
    const float* wrow = UeW + (size_t)(t * 16 + r16) * 64 + 8 * g;
    wF0[t] = cvt8(ld4(wrow),      ld4(wrow + 4));
    wF1[t] = cvt8(ld4(wrow + 32), ld4(wrow + 36));
  }

  // uv = Ueb + Vxe_i (folded once; per-lane channels c = 16t+4g+r)
  const int jti = (bi >> 4) & 15, r16i = bi & 15;
  float uv[4][4];
#pragma unroll
  for (int t = 0; t < 4; ++t) {
    float4 ub = ld4(Ueb + t * 16 + 4 * g);
    float4 vi = ld4(VXEP + ((size_t)((b * 16 + jti) * 4 + t)) * 256 + (g * 16 + r16i) * 4);
    uv[t][0] = ub.x + vi.x; uv[t][1] = ub.y + vi.y;
    uv[t][2] = ub.z + vi.z; uv[t][3] = ub.w + vi.w;
  }

  // prologue: prefetch A tiles 0,1
  float4 A0[4], A1[4];
  loadA(A0, eTile, w * 64 + 0 * 16, r16, g);
  loadA(A1, eTile, w * 64 + 1 * 16, r16, g);

  float sS[4][4] = {}, sQ[4][4] = {}, sA[4][4] = {};

#pragma unroll
  for (int p = 0; p < 4; ++p) {
    const size_t pb = (size_t)((b * 16 + (w * 4 + p)) * 4);
    float4 vj4[4], vn4[4];
#pragma unroll
    for (int t = 0; t < 4; ++t) {
      vj4[t] = ld4(VXEP + (pb + t) * 256 + lane * 4);
      vn4[t] = ld4(VXNP + (pb + t) * 256 + lane * 4);
    }

    float4* As = (p & 1) ? A1 : A0;
    bf16x8 aF0 = cvt8(As[0], As[1]);
    bf16x8 aF1 = cvt8(As[2], As[3]);
    if (p < 2) loadA(As, eTile, w * 64 + (p + 2) * 16, r16, g);

    f32x4 acc[4];
#pragma unroll
    for (int t = 0; t < 4; ++t) {
      f32x4 z = {0.f, 0.f, 0.f, 0.f};
      acc[t] = __builtin_amdgcn_mfma_f32_16x16x32_bf16(wF0[t], aF0, z, 0, 0, 0);
      acc[t] = __builtin_amdgcn_mfma_f32_16x16x32_bf16(wF1[t], aF1, acc[t], 0, 0, 0);
    }

#pragma unroll
    for (int t = 0; t < 4; ++t) {
      float vj[4] = {vj4[t].x, vj4[t].y, vj4[t].z, vj4[t].w};
      float vn[4] = {vn4[t].x, vn4[t].y, vn4[t].z, vn4[t].w};
#pragma unroll
      for (int r = 0; r < 4; ++r) {
        float tv = acc[t][r] + uv[t][r] + vj[r];
        sS[t][r] += tv;
        sQ[t][r]  = fmaf(tv, tv, sQ[t][r]);
        float sg  = __builtin_amdgcn_rcpf(1.0f + __expf(-tv));
        sA[t][r]  = fmaf(sg, vn[r], sA[t][r]);
      }
    }
  }

  // reduce over the 16 j-lanes (bits 0..3 of lane)
#pragma unroll
  for (int t = 0; t < 4; ++t)
#pragma unroll
    for (int r = 0; r < 4; ++r) {
#pragma unroll
      for (int m = 1; m < 16; m <<= 1) {
        sS[t][r] += __shfl_xor(sS[t][r], m);
        sQ[t][r] += __shfl_xor(sQ[t][r], m);
        sA[t][r] += __shfl_xor(sA[t][r], m);
      }
    }

  if (r16 == 0) {
#pragma unroll
    for (int t = 0; t < 4; ++t) {
      const int cb = w * 64 + t * 16 + 4 * g;
      *(float4*)(&redL[cb])       = make_float4(sA[t][0], sA[t][1], sA[t][2], sA[t][3]);
      *(float4*)(&redL[256 + cb]) = make_float4(sS[t][0], sS[t][1], sS[t][2], sS[t][3]);
      *(float4*)(&redL[512 + cb]) = make_float4(sQ[t][0], sQ[t][1], sQ[t][2], sQ[t][3]);
    }
  }
  __syncthreads();
  if (tid < 64) {
    const int c = tid;
    float a  = redL[c]       + redL[64 + c]        + redL[128 + c]       + redL[192 + c];
    ws[WS_AGG + (size_t)bi * 64 + c] = a;
    float s  = redL[256 + c] + redL[256 + 64 + c]  + redL[256 + 128 + c] + redL[256 + 192 + c];
    float qv = redL[512 + c] + redL[512 + 64 + c]  + redL[512 + 128 + c] + redL[512 + 192 + c];
    ws[WS_PART + (size_t)bi * 128 + c]      = s;     // no atomics
    ws[WS_PART + (size_t)bi * 128 + 64 + c] = qv;
  }
}

// ---------------------------------------------------------------------------
// Node path: reduce edge partials -> fold edge-BN scale/shift; then
// x_tmp = Ux + agg ; BN over (B,N) ; relu + residual.
__global__ __launch_bounds__(256) void k_node(
    const float* __restrict__ x,
    const float* __restrict__ bnng, const float* __restrict__ bnnb,
    const float* __restrict__ bneg, const float* __restrict__ bneb,
    float* __restrict__ ws, float* __restrict__ xOut)
{
  const int c = blockIdx.x;
  const int tid = threadIdx.x;
  __shared__ float ss[4], qq[4];
  const int w = tid >> 6;

  float S = 0.f, Q = 0.f;
#pragma unroll
  for (int k = 0; k < 8; ++k) {
    const size_t row = (size_t)(tid + 256 * k) * 128;
    S += ws[WS_PART + row + c];
    Q += ws[WS_PART + row + 64 + c];
  }
#pragma unroll
  for (int m = 1; m < 64; m <<= 1) {
    S += __shfl_xor(S, m);
    Q += __shfl_xor(Q, m);
  }
  if ((tid & 63) == 0) { ss[w] = S; qq[w] = Q; }
  __syncthreads();
  if (tid == 0) {
    float Se = ss[0] + ss[1] + ss[2] + ss[3];
    float Qe = qq[0] + qq[1] + qq[2] + qq[3];
    float mean = Se * INV_EDGE_CNT;
    float var  = Qe * INV_EDGE_CNT - mean * mean;
    float sc = rsqrtf(var + EPSBN) * bneg[c];
    ws[WS_ESUM + c] = sc;
    ws[WS_ESQ  + c] = bneb[c] - mean * sc;
  }
  __syncthreads();

  const float* Ux  = ws + WS_UX;
  const float* agg = ws + WS_AGG;

  float v[8];
  float s = 0.f, q = 0.f;
#pragma unroll
  for (int k = 0; k < 8; ++k) {
    int r = tid + 256 * k;
    float t = Ux[(size_t)r * 64 + c] + agg[(size_t)r * 64 + c];
    v[k] = t;
    s += t;
    q = fmaf(t, t, q);
  }
#pragma unroll
  for (int m = 1; m < 64; m <<= 1) {
    s += __shfl_xor(s, m);
    q += __shfl_xor(q, m);
  }
  if ((tid & 63) == 0) { ss[w] = s; qq[w] = q; }
  __syncthreads();
  float Sn = ss[0] + ss[1] + ss[2] + ss[3];
  float Qn = qq[0] + qq[1] + qq[2] + qq[3];
  float mean = Sn * INV_NODE_CNT;
  float var  = Qn * INV_NODE_CNT - mean * mean;
  float scv = rsqrtf(var + EPSBN) * bnng[c];
  float shv = bnnb[c] - mean * scv;
#pragma unroll
  for (int k = 0; k < 8; ++k) {
    int r = tid + 256 * k;
    float y = fmaf(v[k], scv, shv);
    xOut[(size_t)r * 64 + c] = fmaxf(y, 0.f) + x[(size_t)r * 64 + c];
  }
}

// ---------------------------------------------------------------------------
// Pass C (r8/r14 — best measured): register-staged LDS pipeline, residual
// from the staged LDS tile, prefolded edge BN, float4 stores.
__global__ __launch_bounds__(256) void k_edgeC(
    const float* __restrict__ e,
    const float* __restrict__ UeW, const float* __restrict__ Ueb,
    const float* __restrict__ ws, float* __restrict__ eOut)
{
  __shared__ __align__(16) float eL[4 * 2048];
  __shared__ __align__(16) __bf16 wLds[4096];

  const int tid  = threadIdx.x;
  const int lane = tid & 63;
  const int w    = tid >> 6;
  const int bi   = blockIdx.x;
  const int b    = bi >> 8;
  const int r16  = lane & 15;
  const int g    = lane >> 4;
  const int sw   = r16 & 7;

  const float* eTile = e + (size_t)bi * (Nv * Hv);
  float* myBuf = &eL[w * 2048];
  float* oTile = eOut + (size_t)bi * (Nv * Hv);

#pragma unroll
  for (int k = 0; k < 2; ++k) {
    const int m = tid * 2 + k;
    const int c = m >> 3, p = m & 7;
    float4 lo = ld4(UeW + (size_t)c * 64 + p * 8);
    float4 hi = ld4(UeW + (size_t)c * 64 + p * 8 + 4);
    *(bf16x8*)(&wLds[(size_t)c * 64 + (size_t)(p ^ (c & 7)) * 8]) = cvt8(lo, hi);
  }

  const float* VXEP = ws + WS_VXE;
  const int jti = (bi >> 4) & 15, r16i = bi & 15;
  float4 ueb4[4], vxei4[4], sc4[4], sh4[4];
#pragma unroll
  for (int t = 0; t < 4; ++t) {
    ueb4[t]  = ld4(Ueb + t * 16 + 4 * g);
    vxei4[t] = ld4(VXEP + ((size_t)((b * 16 + jti) * 4 + t)) * 256 + (g * 16 + r16i) * 4);
    sc4[t]   = ld4(ws + WS_ESUM + t * 16 + 4 * g);
    sh4[t]   = ld4(ws + WS_ESQ  + t * 16 + 4 * g);
  }

  float4 Ga[4], Gb[4];
  float4 Pj[2][4];
  load_tile_G(eTile, w, lane, 0, Ga);
  load_tile_G(eTile, w, lane, 1, Gb);
  {
    const size_t pb0 = (size_t)((b * 16 + (w * 4 + 0)) * 4);
#pragma unroll
    for (int t = 0; t < 4; ++t)
      Pj[0][t] = ld4(VXEP + (pb0 + t) * 256 + lane * 4);
  }
  __syncthreads();
  write_tile_L(myBuf, lane, 0, Ga);
  write_tile_L(myBuf, lane, 1, Gb);

#pragma unroll
  for (int p = 0; p < 4; ++p) {
    bf16x8 wF0[4], wF1[4];
#pragma unroll
    for (int t = 0; t < 4; ++t) {
      const int wr = (16 * t + r16) * 64;
      wF0[t] = *(const bf16x8*)(&wLds[wr + ((g ^ sw) << 3)]);
      wF1[t] = *(const bf16x8*)(&wLds[wr + (((4 + g) ^ sw) << 3)]);
    }
    const float* rbase = myBuf + (p & 1) * 1024 + r16 * 64;
    float4 f0 = ld4(rbase + (((2 * g)     ^ sw) << 2));
    float4 f1 = ld4(rbase + (((2 * g + 1) ^ sw) << 2));
    float4 f2 = ld4(rbase + ((((2 * g)     ^ sw) + 8) << 2));
    float4 f3 = ld4(rbase + ((((2 * g + 1) ^ sw) + 8) << 2));
    bf16x8 aF0 = cvt8(f0, f1);
    bf16x8 aF1 = cvt8(f2, f3);
    float4 res4[4];
#pragma unroll
    for (int t = 0; t < 4; ++t)
      res4[t] = ld4(rbase + (((4 * t + g) ^ sw) << 2));

    if (p < 3) {
      const size_t pbn = (size_t)((b * 16 + (w * 4 + p + 1)) * 4);
#pragma unroll
      for (int t = 0; t < 4; ++t)
        Pj[(p + 1) & 1][t] = ld4(VXEP + (pbn + t) * 256 + lane * 4);
    }
    if (p < 2) load_tile_G(eTile, w, lane, p + 2, (p & 1) ? Gb : Ga);

    f32x4 acc[4];
#pragma unroll
    for (int t = 0; t < 4; ++t) {
      f32x4 z = {0.f, 0.f, 0.f, 0.f};
      acc[t] = __builtin_amdgcn_mfma_f32_16x16x32_bf16(wF0[t], aF0, z, 0, 0, 0);
      acc[t] = __builtin_amdgcn_mfma_f32_16x16x32_bf16(wF1[t], aF1, acc[t], 0, 0, 0);
    }

    const int j = w * 64 + p * 16 + r16;
#pragma unroll
    for (int t = 0; t < 4; ++t) {
      float vj[4] = {Pj[p & 1][t].x, Pj[p & 1][t].y, Pj[p & 1][t].z, Pj[p & 1][t].w};
      float rs[4] = {res4[t].x, res4[t].y, res4[t].z, res4[t].w};
      float ub[4] = {ueb4[t].x, ueb4[t].y, ueb4[t].z, ueb4[t].w};
      float vi[4] = {vxei4[t].x, vxei4[t].y, vxei4[t].z, vxei4[t].w};
      float sc[4] = {sc4[t].x, sc4[t].y, sc4[t].z, sc4[t].w};
      float sh[4] = {sh4[t].x, sh4[t].y, sh4[t].z, sh4[t].w};
      float out[4];
#pragma unroll
      for (int r = 0; r < 4; ++r) {
        float tv = acc[t][r] + ub[r] + vi[r] + vj[r];
        float y  = fmaf(tv, sc[r], sh[r]);
        out[r] = fmaxf(y, 0.f) + rs[r];
      }
      *(float4*)(oTile + (size_t)j * 64 + t * 16 + 4 * g) =
          make_float4(out[0], out[1], out[2], out[3]);
    }

    if (p < 2) write_tile_L(myBuf, lane, p & 1, (p & 1) ? Gb : Ga);
    __builtin_amdgcn_sched_barrier(0);
  }
}

// ---------------------------------------------------------------------------
extern "C" void kernel_launch(void* const* d_in, const int* in_sizes, int n_in,
                              void* d_out, int out_size, void* d_ws, size_t ws_size,
                              hipStream_t stream)
{
  const float* x    = (const float*)d_in[0];
  const float* e    = (const float*)d_in[1];
  const float* UeW  = (const float*)d_in[2];
  const float* Ueb  = (const float*)d_in[3];
  const float* VeW  = (const float*)d_in[4];
  const float* Veb  = (const float*)d_in[5];
  const float* UnW  = (const float*)d_in[6];
  const float* Unb  = (const float*)d_in[7];
  const float* VnW  = (const float*)d_in[8];
  const float* Vnb  = (const float*)d_in[9];
  const float* bneg = (const float*)d_in[10];
  const float* bneb = (const float*)d_in[11];
  const float* bnng = (const float*)d_in[12];
  const float* bnnb = (const float*)d_in[13];

  float* ws   = (float*)d_ws;
  float* xOut = (float*)d_out;
  float* eOut = (float*)d_out + (size_t)ROWS * Hv;

  k_lin<<<256, 128, 0, stream>>>(x, VeW, Veb, UnW, Unb, VnW, Vnb, ws);
  k_edgeA<<<ROWS, 256, 0, stream>>>(e, UeW, Ueb, ws);
  k_node<<<Hv, 256, 0, stream>>>(x, bnng, bnnb, bneg, bneb, ws, xOut);
  k_edgeC<<<ROWS, 256, 0, stream>>>(e, UeW, Ueb, ws, eOut);
}

// Round 18
// 112.995 us; speedup vs baseline: 1.7070x; 1.0848x over previous
//
#include <hip/hip_runtime.h>
#include <cstddef>
#include <cstdint>

// Problem constants (B,N,H) = (8,256,64)
constexpr int Bv = 8, Nv = 256, Hv = 64;
constexpr int ROWS = Bv * Nv;            // 2048
constexpr float INV_EDGE_CNT = 1.0f / (8.0f * 256.0f * 256.0f);
constexpr float INV_NODE_CNT = 1.0f / 2048.0f;
constexpr float EPSBN = 1e-5f;

// ws layout (float offsets)
constexpr size_t WS_VXE  = 0;          // [2048*64] PACKED [b][jt][t][lane][4]
constexpr size_t WS_VXN  = 131072;     // [2048*64] PACKED
constexpr size_t WS_UX   = 262144;     // [2048*64] linear [r][c]
constexpr size_t WS_AGG  = 393216;     // [2048*64] linear [r][c]
constexpr size_t WS_ESUM = 524288;     // [64]  k_node writes edge-BN scale
constexpr size_t WS_ESQ  = 524352;     // [64]  k_node writes edge-BN shift
constexpr size_t WS_PART = 524416;     // [2048][128] per-block partial s|q

typedef __bf16 bf16x8 __attribute__((ext_vector_type(8)));
typedef float  f32x4  __attribute__((ext_vector_type(4)));

__device__ __forceinline__ float4 ld4(const float* p) {
  return *reinterpret_cast<const float4*>(p);
}

__device__ __forceinline__ bf16x8 cvt8(float4 a, float4 b) {
  bf16x8 r;
  r[0] = (__bf16)a.x; r[1] = (__bf16)a.y; r[2] = (__bf16)a.z; r[3] = (__bf16)a.w;
  r[4] = (__bf16)b.x; r[5] = (__bf16)b.y; r[6] = (__bf16)b.z; r[7] = (__bf16)b.w;
  return r;
}

// Staging helpers (edgeC skeleton): global tile -> regs with fully-coalesced
// lane-consecutive 16B loads (chunk-swizzled source), then linear LDS write.
__device__ __forceinline__ void load_tile_G(const float* eTile, int w, int lane,
                                            int tt, float4 G[4]) {
#pragma unroll
  for (int k = 0; k < 4; ++k) {
    const int m  = k * 64 + lane;
    const int rl = m >> 4;
    const int pp = m & 15;
    const int cc = pp ^ (rl & 7);
    G[k] = ld4(eTile + (size_t)(w * 64 + tt * 16 + rl) * 64 + cc * 4);
  }
}

__device__ __forceinline__ void write_tile_L(float* myBuf, int lane, int s,
                                             const float4 G[4]) {
#pragma unroll
  for (int k = 0; k < 4; ++k)
    *(float4*)(myBuf + s * 1024 + k * 256 + lane * 4) = G[k];
}

#define DOT4(acc, a, b) \
  acc = fmaf((a).x, (b).x, fmaf((a).y, (b).y, fmaf((a).z, (b).z, fmaf((a).w, (b).w, acc))))

// ---------------------------------------------------------------------------
// Linears: Vxe / Vxn written PACKED f32 for the edge-kernel epilogue lane
// order; Ux linear. 256 blocks x 128 threads (full-GPU spread).
__global__ __launch_bounds__(128) void k_lin(
    const float* __restrict__ x,
    const float* __restrict__ VeW, const float* __restrict__ Veb,
    const float* __restrict__ UnW, const float* __restrict__ Unb,
    const float* __restrict__ VnW, const float* __restrict__ Vnb,
    float* __restrict__ ws)
{
  const int idx = blockIdx.x * 128 + threadIdx.x;   // 32768 total
  const int r  = idx >> 4;           // row 0..2047
  const int tg = idx & 15;
  const int t  = tg >> 2, g = tg & 3;
  const int c0 = t * 16 + g * 4;

  const float4* x4 = (const float4*)(x + (size_t)r * 64);
  float a1[4] = {}, a2[4] = {}, a3[4] = {};
#pragma unroll
  for (int h = 0; h < 16; ++h) {
    float4 xv = x4[h];
#pragma unroll
    for (int cc = 0; cc < 4; ++cc) {
      float4 w1 = ld4(VeW + (size_t)(c0 + cc) * 64 + h * 4); DOT4(a1[cc], xv, w1);
      float4 w2 = ld4(UnW + (size_t)(c0 + cc) * 64 + h * 4); DOT4(a2[cc], xv, w2);
      float4 w3 = ld4(VnW + (size_t)(c0 + cc) * 64 + h * 4); DOT4(a3[cc], xv, w3);
    }
  }

  const int b = r >> 8, jt = (r >> 4) & 15, r16 = r & 15;
  const size_t pidx = ((size_t)((b * 16 + jt) * 4 + t)) * 256 + (g * 16 + r16) * 4;
  *(float4*)(&ws[WS_VXE + pidx]) =
      make_float4(a1[0] + Veb[c0], a1[1] + Veb[c0 + 1], a1[2] + Veb[c0 + 2], a1[3] + Veb[c0 + 3]);
  *(float4*)(&ws[WS_VXN + pidx]) =
      make_float4(a3[0] + Vnb[c0], a3[1] + Vnb[c0 + 1], a3[2] + Vnb[c0 + 2], a3[3] + Vnb[c0 + 3]);
  *(float4*)(&ws[WS_UX + (size_t)r * 64 + c0]) =
      make_float4(a2[0] + Unb[c0], a2[1] + Unb[c0 + 1], a2[2] + Unb[c0 + 2], a2[3] + Unb[c0 + 3]);
}

// ---------------------------------------------------------------------------
// Pass A on the edgeC skeleton: W->LDS once; e staged via coalesced
// reg->LDS pipeline; swizzled LDS fragment reads; sigmoid/stats epilogue;
// reduce tail through the idle staging LDS. No store of e_tmp, no atomics.
__global__ __launch_bounds__(256) void k_edgeA(
    const float* __restrict__ e,
    const float* __restrict__ UeW, const float* __restrict__ Ueb,
    float* __restrict__ ws)
{
  __shared__ __align__(16) float eL[4 * 2048];     // 32KB tiles (+reduce reuse)
  __shared__ __align__(16) __bf16 wLds[4096];      // 8KB W, chunk-swizzled

  const int tid  = threadIdx.x;
  const int lane = tid & 63;
  const int w    = tid >> 6;
  const int bi   = blockIdx.x;
  const int b    = bi >> 8;
  const int r16  = lane & 15;
  const int g    = lane >> 4;
  const int sw   = r16 & 7;

  const float* eTile = e + (size_t)bi * (Nv * Hv);
  float* myBuf = &eL[w * 2048];

  // stage W -> LDS (bf16, chunk p of row c stored at p ^ (c&7)), coalesced
#pragma unroll
  for (int k = 0; k < 2; ++k) {
    const int m = tid * 2 + k;
    const int c = m >> 3, p = m & 7;
    float4 lo = ld4(UeW + (size_t)c * 64 + p * 8);
    float4 hi = ld4(UeW + (size_t)c * 64 + p * 8 + 4);
    *(bf16x8*)(&wLds[(size_t)c * 64 + (size_t)(p ^ (c & 7)) * 8]) = cvt8(lo, hi);
  }

  const float* VXEP = ws + WS_VXE;
  const float* VXNP = ws + WS_VXN;

  // uv = Ueb + Vxe_i (folded once; per-lane channels c = 16t+4g+r)
  const int jti = (bi >> 4) & 15, r16i = bi & 15;
  float uv[4][4];
#pragma unroll
  for (int t = 0; t < 4; ++t) {
    float4 ub = ld4(Ueb + t * 16 + 4 * g);
    float4 vi = ld4(VXEP + ((size_t)((b * 16 + jti) * 4 + t)) * 256 + (g * 16 + r16i) * 4);
    uv[t][0] = ub.x + vi.x; uv[t][1] = ub.y + vi.y;
    uv[t][2] = ub.z + vi.z; uv[t][3] = ub.w + vi.w;
  }

  // prologue: tiles 0,1 -> regs -> LDS
  float4 Ga[4], Gb[4];
  load_tile_G(eTile, w, lane, 0, Ga);
  load_tile_G(eTile, w, lane, 1, Gb);
  __syncthreads();                       // wLds ready
  write_tile_L(myBuf, lane, 0, Ga);
  write_tile_L(myBuf, lane, 1, Gb);

  // W fragments from LDS once
  bf16x8 wF0[4], wF1[4];
#pragma unroll
  for (int t = 0; t < 4; ++t) {
    const int wr = (16 * t + r16) * 64;
    wF0[t] = *(const bf16x8*)(&wLds[wr + ((g ^ sw) << 3)]);
    wF1[t] = *(const bf16x8*)(&wLds[wr + (((4 + g) ^ sw) << 3)]);
  }

  float sS[4][4] = {}, sQ[4][4] = {}, sA[4][4] = {};

#pragma unroll
  for (int p = 0; p < 4; ++p) {
    // packed epilogue loads for this phase (in flight during LDS reads+MFMA)
    const size_t pb = (size_t)((b * 16 + (w * 4 + p)) * 4);
    float4 vj4[4], vn4[4];
#pragma unroll
    for (int t = 0; t < 4; ++t) {
      vj4[t] = ld4(VXEP + (pb + t) * 256 + lane * 4);
      vn4[t] = ld4(VXNP + (pb + t) * 256 + lane * 4);
    }

    const float* rbase = myBuf + (p & 1) * 1024 + r16 * 64;
    float4 f0 = ld4(rbase + (((2 * g)     ^ sw) << 2));
    float4 f1 = ld4(rbase + (((2 * g + 1) ^ sw) << 2));
    float4 f2 = ld4(rbase + ((((2 * g)     ^ sw) + 8) << 2));
    float4 f3 = ld4(rbase + ((((2 * g + 1) ^ sw) + 8) << 2));
    bf16x8 aF0 = cvt8(f0, f1);
    bf16x8 aF1 = cvt8(f2, f3);

    if (p < 2) load_tile_G(eTile, w, lane, p + 2, (p & 1) ? Gb : Ga);

    f32x4 acc[4];
#pragma unroll
    for (int t = 0; t < 4; ++t) {
      f32x4 z = {0.f, 0.f, 0.f, 0.f};
      acc[t] = __builtin_amdgcn_mfma_f32_16x16x32_bf16(wF0[t], aF0, z, 0, 0, 0);
      acc[t] = __builtin_amdgcn_mfma_f32_16x16x32_bf16(wF1[t], aF1, acc[t], 0, 0, 0);
    }

#pragma unroll
    for (int t = 0; t < 4; ++t) {
      float vj[4] = {vj4[t].x, vj4[t].y, vj4[t].z, vj4[t].w};
      float vn[4] = {vn4[t].x, vn4[t].y, vn4[t].z, vn4[t].w};
#pragma unroll
      for (int r = 0; r < 4; ++r) {
        float tv = acc[t][r] + uv[t][r] + vj[r];
        sS[t][r] += tv;
        sQ[t][r]  = fmaf(tv, tv, sQ[t][r]);
        float sg  = __builtin_amdgcn_rcpf(1.0f + __expf(-tv));
        sA[t][r]  = fmaf(sg, vn[r], sA[t][r]);
      }
    }

    // write tile p+2 into the buffer just consumed (in-order LDS per wave)
    if (p < 2) write_tile_L(myBuf, lane, p & 1, (p & 1) ? Gb : Ga);
    __builtin_amdgcn_sched_barrier(0);
  }

  // reduce over the 16 j-lanes (bits 0..3 of lane)
#pragma unroll
  for (int t = 0; t < 4; ++t)
#pragma unroll
    for (int r = 0; r < 4; ++r) {
#pragma unroll
      for (int m = 1; m < 16; m <<= 1) {
        sS[t][r] += __shfl_xor(sS[t][r], m);
        sQ[t][r] += __shfl_xor(sQ[t][r], m);
        sA[t][r] += __shfl_xor(sA[t][r], m);
      }
    }

  // per-wave partials into the wave's own (now idle) staging region
  if (r16 == 0) {
#pragma unroll
    for (int t = 0; t < 4; ++t) {
      const int cb = t * 16 + 4 * g;
      *(float4*)(&myBuf[cb])       = make_float4(sA[t][0], sA[t][1], sA[t][2], sA[t][3]);
      *(float4*)(&myBuf[256 + cb]) = make_float4(sS[t][0], sS[t][1], sS[t][2], sS[t][3]);
      *(float4*)(&myBuf[512 + cb]) = make_float4(sQ[t][0], sQ[t][1], sQ[t][2], sQ[t][3]);
    }
  }
  __syncthreads();
  if (tid < 64) {
    const int c = tid;
    float a  = eL[c]       + eL[2048 + c]       + eL[4096 + c]       + eL[6144 + c];
    ws[WS_AGG + (size_t)bi * 64 + c] = a;
    float s  = eL[256 + c] + eL[2048 + 256 + c] + eL[4096 + 256 + c] + eL[6144 + 256 + c];
    float qv = eL[512 + c] + eL[2048 + 512 + c] + eL[4096 + 512 + c] + eL[6144 + 512 + c];
    ws[WS_PART + (size_t)bi * 128 + c]      = s;     // no atomics
    ws[WS_PART + (size_t)bi * 128 + 64 + c] = qv;
  }
}

// ---------------------------------------------------------------------------
// Node path: reduce edge partials -> fold edge-BN scale/shift; then
// x_tmp = Ux + agg ; BN over (B,N) ; relu + residual.
__global__ __launch_bounds__(256) void k_node(
    const float* __restrict__ x,
    const float* __restrict__ bnng, const float* __restrict__ bnnb,
    const float* __restrict__ bneg, const float* __restrict__ bneb,
    float* __restrict__ ws, float* __restrict__ xOut)
{
  const int c = blockIdx.x;
  const int tid = threadIdx.x;
  __shared__ float ss[4], qq[4];
  const int w = tid >> 6;

  float S = 0.f, Q = 0.f;
#pragma unroll
  for (int k = 0; k < 8; ++k) {
    const size_t row = (size_t)(tid + 256 * k) * 128;
    S += ws[WS_PART + row + c];
    Q += ws[WS_PART + row + 64 + c];
  }
#pragma unroll
  for (int m = 1; m < 64; m <<= 1) {
    S += __shfl_xor(S, m);
    Q += __shfl_xor(Q, m);
  }
  if ((tid & 63) == 0) { ss[w] = S; qq[w] = Q; }
  __syncthreads();
  if (tid == 0) {
    float Se = ss[0] + ss[1] + ss[2] + ss[3];
    float Qe = qq[0] + qq[1] + qq[2] + qq[3];
    float mean = Se * INV_EDGE_CNT;
    float var  = Qe * INV_EDGE_CNT - mean * mean;
    float sc = rsqrtf(var + EPSBN) * bneg[c];
    ws[WS_ESUM + c] = sc;
    ws[WS_ESQ  + c] = bneb[c] - mean * sc;
  }
  __syncthreads();

  const float* Ux  = ws + WS_UX;
  const float* agg = ws + WS_AGG;

  float v[8];
  float s = 0.f, q = 0.f;
#pragma unroll
  for (int k = 0; k < 8; ++k) {
    int r = tid + 256 * k;
    float t = Ux[(size_t)r * 64 + c] + agg[(size_t)r * 64 + c];
    v[k] = t;
    s += t;
    q = fmaf(t, t, q);
  }
#pragma unroll
  for (int m = 1; m < 64; m <<= 1) {
    s += __shfl_xor(s, m);
    q += __shfl_xor(q, m);
  }
  if ((tid & 63) == 0) { ss[w] = s; qq[w] = q; }
  __syncthreads();
  float Sn = ss[0] + ss[1] + ss[2] + ss[3];
  float Qn = qq[0] + qq[1] + qq[2] + qq[3];
  float mean = Sn * INV_NODE_CNT;
  float var  = Qn * INV_NODE_CNT - mean * mean;
  float scv = rsqrtf(var + EPSBN) * bnng[c];
  float shv = bnnb[c] - mean * scv;
#pragma unroll
  for (int k = 0; k < 8; ++k) {
    int r = tid + 256 * k;
    float y = fmaf(v[k], scv, shv);
    xOut[(size_t)r * 64 + c] = fmaxf(y, 0.f) + x[(size_t)r * 64 + c];
  }
}

// ---------------------------------------------------------------------------
// Pass C (r8/r14 — best measured, at its BW roofline): register-staged LDS
// pipeline, residual from the staged LDS tile, prefolded edge BN.
__global__ __launch_bounds__(256) void k_edgeC(
    const float* __restrict__ e,
    const float* __restrict__ UeW, const float* __restrict__ Ueb,
    const float* __restrict__ ws, float* __restrict__ eOut)
{
  __shared__ __align__(16) float eL[4 * 2048];
  __shared__ __align__(16) __bf16 wLds[4096];

  const int tid  = threadIdx.x;
  const int lane = tid & 63;
  const int w    = tid >> 6;
  const int bi   = blockIdx.x;
  const int b    = bi >> 8;
  const int r16  = lane & 15;
  const int g    = lane >> 4;
  const int sw   = r16 & 7;

  const float* eTile = e + (size_t)bi * (Nv * Hv);
  float* myBuf = &eL[w * 2048];
  float* oTile = eOut + (size_t)bi * (Nv * Hv);

#pragma unroll
  for (int k = 0; k < 2; ++k) {
    const int m = tid * 2 + k;
    const int c = m >> 3, p = m & 7;
    float4 lo = ld4(UeW + (size_t)c * 64 + p * 8);
    float4 hi = ld4(UeW + (size_t)c * 64 + p * 8 + 4);
    *(bf16x8*)(&wLds[(size_t)c * 64 + (size_t)(p ^ (c & 7)) * 8]) = cvt8(lo, hi);
  }

  const float* VXEP = ws + WS_VXE;
  const int jti = (bi >> 4) & 15, r16i = bi & 15;
  float4 ueb4[4], vxei4[4], sc4[4], sh4[4];
#pragma unroll
  for (int t = 0; t < 4; ++t) {
    ueb4[t]  = ld4(Ueb + t * 16 + 4 * g);
    vxei4[t] = ld4(VXEP + ((size_t)((b * 16 + jti) * 4 + t)) * 256 + (g * 16 + r16i) * 4);
    sc4[t]   = ld4(ws + WS_ESUM + t * 16 + 4 * g);
    sh4[t]   = ld4(ws + WS_ESQ  + t * 16 + 4 * g);
  }

  float4 Ga[4], Gb[4];
  float4 Pj[2][4];
  load_tile_G(eTile, w, lane, 0, Ga);
  load_tile_G(eTile, w, lane, 1, Gb);
  {
    const size_t pb0 = (size_t)((b * 16 + (w * 4 + 0)) * 4);
#pragma unroll
    for (int t = 0; t < 4; ++t)
      Pj[0][t] = ld4(VXEP + (pb0 + t) * 256 + lane * 4);
  }
  __syncthreads();
  write_tile_L(myBuf, lane, 0, Ga);
  write_tile_L(myBuf, lane, 1, Gb);

#pragma unroll
  for (int p = 0; p < 4; ++p) {
    bf16x8 wF0[4], wF1[4];
#pragma unroll
    for (int t = 0; t < 4; ++t) {
      const int wr = (16 * t + r16) * 64;
      wF0[t] = *(const bf16x8*)(&wLds[wr + ((g ^ sw) << 3)]);
      wF1[t] = *(const bf16x8*)(&wLds[wr + (((4 + g) ^ sw) << 3)]);
    }
    const float* rbase = myBuf + (p & 1) * 1024 + r16 * 64;
    float4 f0 = ld4(rbase + (((2 * g)     ^ sw) << 2));
    float4 f1 = ld4(rbase + (((2 * g + 1) ^ sw) << 2));
    float4 f2 = ld4(rbase + ((((2 * g)     ^ sw) + 8) << 2));
    float4 f3 = ld4(rbase + ((((2 * g + 1) ^ sw) + 8) << 2));
    bf16x8 aF0 = cvt8(f0, f1);
    bf16x8 aF1 = cvt8(f2, f3);
    float4 res4[4];
#pragma unroll
    for (int t = 0; t < 4; ++t)
      res4[t] = ld4(rbase + (((4 * t + g) ^ sw) << 2));

    if (p < 3) {
      const size_t pbn = (size_t)((b * 16 + (w * 4 + p + 1)) * 4);
#pragma unroll
      for (int t = 0; t < 4; ++t)
        Pj[(p + 1) & 1][t] = ld4(VXEP + (pbn + t) * 256 + lane * 4);
    }
    if (p < 2) load_tile_G(eTile, w, lane, p + 2, (p & 1) ? Gb : Ga);

    f32x4 acc[4];
#pragma unroll
    for (int t = 0; t < 4; ++t) {
      f32x4 z = {0.f, 0.f, 0.f, 0.f};
      acc[t] = __builtin_amdgcn_mfma_f32_16x16x32_bf16(wF0[t], aF0, z, 0, 0, 0);
      acc[t] = __builtin_amdgcn_mfma_f32_16x16x32_bf16(wF1[t], aF1, acc[t], 0, 0, 0);
    }

    const int j = w * 64 + p * 16 + r16;
#pragma unroll
    for (int t = 0; t < 4; ++t) {
      float vj[4] = {Pj[p & 1][t].x, Pj[p & 1][t].y, Pj[p & 1][t].z, Pj[p & 1][t].w};
      float rs[4] = {res4[t].x, res4[t].y, res4[t].z, res4[t].w};
      float ub[4] = {ueb4[t].x, ueb4[t].y, ueb4[t].z, ueb4[t].w};
      float vi[4] = {vxei4[t].x, vxei4[t].y, vxei4[t].z, vxei4[t].w};
      float sc[4] = {sc4[t].x, sc4[t].y, sc4[t].z, sc4[t].w};
      float sh[4] = {sh4[t].x, sh4[t].y, sh4[t].z, sh4[t].w};
      float out[4];
#pragma unroll
      for (int r = 0; r < 4; ++r) {
        float tv = acc[t][r] + ub[r] + vi[r] + vj[r];
        float y  = fmaf(tv, sc[r], sh[r]);
        out[r] = fmaxf(y, 0.f) + rs[r];
      }
      *(float4*)(oTile + (size_t)j * 64 + t * 16 + 4 * g) =
          make_float4(out[0], out[1], out[2], out[3]);
    }

    if (p < 2) write_tile_L(myBuf, lane, p & 1, (p & 1) ? Gb : Ga);
    __builtin_amdgcn_sched_barrier(0);
  }
}

// ---------------------------------------------------------------------------
extern "C" void kernel_launch(void* const* d_in, const int* in_sizes, int n_in,
                              void* d_out, int out_size, void* d_ws, size_t ws_size,
                              hipStream_t stream)
{
  const float* x    = (const float*)d_in[0];
  const float* e    = (const float*)d_in[1];
  const float* UeW  = (const float*)d_in[2];
  const float* Ueb  = (const float*)d_in[3];
  const float* VeW  = (const float*)d_in[4];
  const float* Veb  = (const float*)d_in[5];
  const float* UnW  = (const float*)d_in[6];
  const float* Unb  = (const float*)d_in[7];
  const float* VnW  = (const float*)d_in[8];
  const float* Vnb  = (const float*)d_in[9];
  const float* bneg = (const float*)d_in[10];
  const float* bneb = (const float*)d_in[11];
  const float* bnng = (const float*)d_in[12];
  const float* bnnb = (const float*)d_in[13];

  float* ws   = (float*)d_ws;
  float* xOut = (float*)d_out;
  float* eOut = (float*)d_out + (size_t)ROWS * Hv;

  k_lin<<<256, 128, 0, stream>>>(x, VeW, Veb, UnW, Unb, VnW, Vnb, ws);
  k_edgeA<<<ROWS, 256, 0, stream>>>(e, UeW, Ueb, ws);
  k_node<<<Hv, 256, 0, stream>>>(x, bnng, bnnb, bneg, bneb, ws, xOut);
  k_edgeC<<<ROWS, 256, 0, stream>>>(e, UeW, Ueb, ws, eOut);
}

// Round 19
// 110.264 us; speedup vs baseline: 1.7492x; 1.0248x over previous
//
#include <hip/hip_runtime.h>
#include <cstddef>
#include <cstdint>

// Problem constants (B,N,H) = (8,256,64)
constexpr int Bv = 8, Nv = 256, Hv = 64;
constexpr int ROWS = Bv * Nv;            // 2048
constexpr float INV_EDGE_CNT = 1.0f / (8.0f * 256.0f * 256.0f);
constexpr float INV_NODE_CNT = 1.0f / 2048.0f;
constexpr float EPSBN = 1e-5f;

// ws layout (float offsets)
constexpr size_t WS_VXE  = 0;          // [2048*64] PACKED [b][jt][t][lane][4]
constexpr size_t WS_VXN  = 131072;     // [2048*64] PACKED
constexpr size_t WS_UX   = 262144;     // [2048*64] linear [r][c]
constexpr size_t WS_AGG  = 393216;     // [2048*64] linear [r][c]
constexpr size_t WS_ESUM = 524288;     // [64]  k_node writes edge-BN scale
constexpr size_t WS_ESQ  = 524352;     // [64]  k_node writes edge-BN shift
constexpr size_t WS_PART = 524416;     // [2048][128] per-block partial s|q

typedef __bf16 bf16x8 __attribute__((ext_vector_type(8)));
typedef float  f32x4  __attribute__((ext_vector_type(4)));

__device__ __forceinline__ float4 ld4(const float* p) {
  return *reinterpret_cast<const float4*>(p);
}

__device__ __forceinline__ bf16x8 cvt8(float4 a, float4 b) {
  bf16x8 r;
  r[0] = (__bf16)a.x; r[1] = (__bf16)a.y; r[2] = (__bf16)a.z; r[3] = (__bf16)a.w;
  r[4] = (__bf16)b.x; r[5] = (__bf16)b.y; r[6] = (__bf16)b.z; r[7] = (__bf16)b.w;
  return r;
}

// Staging helpers: global tile -> regs with fully-coalesced lane-consecutive
// 16B loads (chunk-swizzled source), then linear LDS write.
__device__ __forceinline__ void load_tile_G(const float* eTile, int w, int lane,
                                            int tt, float4 G[4]) {
#pragma unroll
  for (int k = 0; k < 4; ++k) {
    const int m  = k * 64 + lane;
    const int rl = m >> 4;
    const int pp = m & 15;
    const int cc = pp ^ (rl & 7);
    G[k] = ld4(eTile + (size_t)(w * 64 + tt * 16 + rl) * 64 + cc * 4);
  }
}

__device__ __forceinline__ void write_tile_L(float* myBuf, int lane, int s,
                                             const float4 G[4]) {
#pragma unroll
  for (int k = 0; k < 4; ++k)
    *(float4*)(myBuf + s * 1024 + k * 256 + lane * 4) = G[k];
}

#define DOT4(acc, a, b) \
  acc = fmaf((a).x, (b).x, fmaf((a).y, (b).y, fmaf((a).z, (b).z, fmaf((a).w, (b).w, acc))))

// ---------------------------------------------------------------------------
// Linears: Vxe / Vxn written PACKED f32 for the edge-kernel epilogue lane
// order; Ux linear. 256 blocks x 128 threads (full-GPU spread).
__global__ __launch_bounds__(128) void k_lin(
    const float* __restrict__ x,
    const float* __restrict__ VeW, const float* __restrict__ Veb,
    const float* __restrict__ UnW, const float* __restrict__ Unb,
    const float* __restrict__ VnW, const float* __restrict__ Vnb,
    float* __restrict__ ws)
{
  const int idx = blockIdx.x * 128 + threadIdx.x;   // 32768 total
  const int r  = idx >> 4;           // row 0..2047
  const int tg = idx & 15;
  const int t  = tg >> 2, g = tg & 3;
  const int c0 = t * 16 + g * 4;

  const float4* x4 = (const float4*)(x + (size_t)r * 64);
  float a1[4] = {}, a2[4] = {}, a3[4] = {};
#pragma unroll
  for (int h = 0; h < 16; ++h) {
    float4 xv = x4[h];
#pragma unroll
    for (int cc = 0; cc < 4; ++cc) {
      float4 w1 = ld4(VeW + (size_t)(c0 + cc) * 64 + h * 4); DOT4(a1[cc], xv, w1);
      float4 w2 = ld4(UnW + (size_t)(c0 + cc) * 64 + h * 4); DOT4(a2[cc], xv, w2);
      float4 w3 = ld4(VnW + (size_t)(c0 + cc) * 64 + h * 4); DOT4(a3[cc], xv, w3);
    }
  }

  const int b = r >> 8, jt = (r >> 4) & 15, r16 = r & 15;
  const size_t pidx = ((size_t)((b * 16 + jt) * 4 + t)) * 256 + (g * 16 + r16) * 4;
  *(float4*)(&ws[WS_VXE + pidx]) =
      make_float4(a1[0] + Veb[c0], a1[1] + Veb[c0 + 1], a1[2] + Veb[c0 + 2], a1[3] + Veb[c0 + 3]);
  *(float4*)(&ws[WS_VXN + pidx]) =
      make_float4(a3[0] + Vnb[c0], a3[1] + Vnb[c0 + 1], a3[2] + Vnb[c0 + 2], a3[3] + Vnb[c0 + 3]);
  *(float4*)(&ws[WS_UX + (size_t)r * 64 + c0]) =
      make_float4(a2[0] + Unb[c0], a2[1] + Unb[c0 + 1], a2[2] + Unb[c0 + 2], a2[3] + Unb[c0 + 3]);
}

// ---------------------------------------------------------------------------
// Pass A (edgeC skeleton + one-phase-ahead packed prefetch): W->LDS once;
// e staged via coalesced reg->LDS pipeline; vj/vn double-buffered one phase
// ahead (latency hidden under previous phase's LDS reads + MFMA);
// sigmoid/stats epilogue; reduce tail through the idle staging LDS.
__global__ __launch_bounds__(256) void k_edgeA(
    const float* __restrict__ e,
    const float* __restrict__ UeW, const float* __restrict__ Ueb,
    float* __restrict__ ws)
{
  __shared__ __align__(16) float eL[4 * 2048];     // 32KB tiles (+reduce reuse)
  __shared__ __align__(16) __bf16 wLds[4096];      // 8KB W, chunk-swizzled

  const int tid  = threadIdx.x;
  const int lane = tid & 63;
  const int w    = tid >> 6;
  const int bi   = blockIdx.x;
  const int b    = bi >> 8;
  const int r16  = lane & 15;
  const int g    = lane >> 4;
  const int sw   = r16 & 7;

  const float* eTile = e + (size_t)bi * (Nv * Hv);
  float* myBuf = &eL[w * 2048];

  // stage W -> LDS (bf16, chunk p of row c stored at p ^ (c&7)), coalesced
#pragma unroll
  for (int k = 0; k < 2; ++k) {
    const int m = tid * 2 + k;
    const int c = m >> 3, p = m & 7;
    float4 lo = ld4(UeW + (size_t)c * 64 + p * 8);
    float4 hi = ld4(UeW + (size_t)c * 64 + p * 8 + 4);
    *(bf16x8*)(&wLds[(size_t)c * 64 + (size_t)(p ^ (c & 7)) * 8]) = cvt8(lo, hi);
  }

  const float* VXEP = ws + WS_VXE;
  const float* VXNP = ws + WS_VXN;

  // uv = Ueb + Vxe_i (folded once; per-lane channels c = 16t+4g+r)
  const int jti = (bi >> 4) & 15, r16i = bi & 15;
  float uv[4][4];
#pragma unroll
  for (int t = 0; t < 4; ++t) {
    float4 ub = ld4(Ueb + t * 16 + 4 * g);
    float4 vi = ld4(VXEP + ((size_t)((b * 16 + jti) * 4 + t)) * 256 + (g * 16 + r16i) * 4);
    uv[t][0] = ub.x + vi.x; uv[t][1] = ub.y + vi.y;
    uv[t][2] = ub.z + vi.z; uv[t][3] = ub.w + vi.w;
  }

  // prologue: tiles 0,1 -> regs; packed phase-0 loads in flight
  float4 Ga[4], Gb[4];
  float4 Pj[2][4], Pn[2][4];
  load_tile_G(eTile, w, lane, 0, Ga);
  load_tile_G(eTile, w, lane, 1, Gb);
  {
    const size_t pb0 = (size_t)((b * 16 + (w * 4 + 0)) * 4);
#pragma unroll
    for (int t = 0; t < 4; ++t) {
      Pj[0][t] = ld4(VXEP + (pb0 + t) * 256 + lane * 4);
      Pn[0][t] = ld4(VXNP + (pb0 + t) * 256 + lane * 4);
    }
  }
  __syncthreads();                       // wLds ready
  write_tile_L(myBuf, lane, 0, Ga);
  write_tile_L(myBuf, lane, 1, Gb);

  // W fragments from LDS once
  bf16x8 wF0[4], wF1[4];
#pragma unroll
  for (int t = 0; t < 4; ++t) {
    const int wr = (16 * t + r16) * 64;
    wF0[t] = *(const bf16x8*)(&wLds[wr + ((g ^ sw) << 3)]);
    wF1[t] = *(const bf16x8*)(&wLds[wr + (((4 + g) ^ sw) << 3)]);
  }

  float sS[4][4] = {}, sQ[4][4] = {}, sA[4][4] = {};

#pragma unroll
  for (int p = 0; p < 4; ++p) {
    const float* rbase = myBuf + (p & 1) * 1024 + r16 * 64;
    float4 f0 = ld4(rbase + (((2 * g)     ^ sw) << 2));
    float4 f1 = ld4(rbase + (((2 * g + 1) ^ sw) << 2));
    float4 f2 = ld4(rbase + ((((2 * g)     ^ sw) + 8) << 2));
    float4 f3 = ld4(rbase + ((((2 * g + 1) ^ sw) + 8) << 2));
    bf16x8 aF0 = cvt8(f0, f1);
    bf16x8 aF1 = cvt8(f2, f3);

    // prefetch: packed panel for p+1, tile p+2 (full phase in flight)
    if (p < 3) {
      const size_t pbn = (size_t)((b * 16 + (w * 4 + p + 1)) * 4);
#pragma unroll
      for (int t = 0; t < 4; ++t) {
        Pj[(p + 1) & 1][t] = ld4(VXEP + (pbn + t) * 256 + lane * 4);
        Pn[(p + 1) & 1][t] = ld4(VXNP + (pbn + t) * 256 + lane * 4);
      }
    }
    if (p < 2) load_tile_G(eTile, w, lane, p + 2, (p & 1) ? Gb : Ga);

    f32x4 acc[4];
#pragma unroll
    for (int t = 0; t < 4; ++t) {
      f32x4 z = {0.f, 0.f, 0.f, 0.f};
      acc[t] = __builtin_amdgcn_mfma_f32_16x16x32_bf16(wF0[t], aF0, z, 0, 0, 0);
      acc[t] = __builtin_amdgcn_mfma_f32_16x16x32_bf16(wF1[t], aF1, acc[t], 0, 0, 0);
    }

#pragma unroll
    for (int t = 0; t < 4; ++t) {
      float vj[4] = {Pj[p & 1][t].x, Pj[p & 1][t].y, Pj[p & 1][t].z, Pj[p & 1][t].w};
      float vn[4] = {Pn[p & 1][t].x, Pn[p & 1][t].y, Pn[p & 1][t].z, Pn[p & 1][t].w};
#pragma unroll
      for (int r = 0; r < 4; ++r) {
        float tv = acc[t][r] + uv[t][r] + vj[r];
        sS[t][r] += tv;
        sQ[t][r]  = fmaf(tv, tv, sQ[t][r]);
        float sg  = __builtin_amdgcn_rcpf(1.0f + __expf(-tv));
        sA[t][r]  = fmaf(sg, vn[r], sA[t][r]);
      }
    }

    // write tile p+2 into the buffer just consumed (in-order LDS per wave)
    if (p < 2) write_tile_L(myBuf, lane, p & 1, (p & 1) ? Gb : Ga);
    __builtin_amdgcn_sched_barrier(0);
  }

  // reduce over the 16 j-lanes (bits 0..3 of lane)
#pragma unroll
  for (int t = 0; t < 4; ++t)
#pragma unroll
    for (int r = 0; r < 4; ++r) {
#pragma unroll
      for (int m = 1; m < 16; m <<= 1) {
        sS[t][r] += __shfl_xor(sS[t][r], m);
        sQ[t][r] += __shfl_xor(sQ[t][r], m);
        sA[t][r] += __shfl_xor(sA[t][r], m);
      }
    }

  // per-wave partials into the wave's own (now idle) staging region
  if (r16 == 0) {
#pragma unroll
    for (int t = 0; t < 4; ++t) {
      const int cb = t * 16 + 4 * g;
      *(float4*)(&myBuf[cb])       = make_float4(sA[t][0], sA[t][1], sA[t][2], sA[t][3]);
      *(float4*)(&myBuf[256 + cb]) = make_float4(sS[t][0], sS[t][1], sS[t][2], sS[t][3]);
      *(float4*)(&myBuf[512 + cb]) = make_float4(sQ[t][0], sQ[t][1], sQ[t][2], sQ[t][3]);
    }
  }
  __syncthreads();
  if (tid < 64) {
    const int c = tid;
    float a  = eL[c]       + eL[2048 + c]       + eL[4096 + c]       + eL[6144 + c];
    ws[WS_AGG + (size_t)bi * 64 + c] = a;
    float s  = eL[256 + c] + eL[2048 + 256 + c] + eL[4096 + 256 + c] + eL[6144 + 256 + c];
    float qv = eL[512 + c] + eL[2048 + 512 + c] + eL[4096 + 512 + c] + eL[6144 + 512 + c];
    ws[WS_PART + (size_t)bi * 128 + c]      = s;     // no atomics
    ws[WS_PART + (size_t)bi * 128 + 64 + c] = qv;
  }
}

// ---------------------------------------------------------------------------
// Node path: reduce edge partials -> fold edge-BN scale/shift; then
// x_tmp = Ux + agg ; BN over (B,N) ; relu + residual.
__global__ __launch_bounds__(256) void k_node(
    const float* __restrict__ x,
    const float* __restrict__ bnng, const float* __restrict__ bnnb,
    const float* __restrict__ bneg, const float* __restrict__ bneb,
    float* __restrict__ ws, float* __restrict__ xOut)
{
  const int c = blockIdx.x;
  const int tid = threadIdx.x;
  __shared__ float ss[4], qq[4];
  const int w = tid >> 6;

  float S = 0.f, Q = 0.f;
#pragma unroll
  for (int k = 0; k < 8; ++k) {
    const size_t row = (size_t)(tid + 256 * k) * 128;
    S += ws[WS_PART + row + c];
    Q += ws[WS_PART + row + 64 + c];
  }
#pragma unroll
  for (int m = 1; m < 64; m <<= 1) {
    S += __shfl_xor(S, m);
    Q += __shfl_xor(Q, m);
  }
  if ((tid & 63) == 0) { ss[w] = S; qq[w] = Q; }
  __syncthreads();
  if (tid == 0) {
    float Se = ss[0] + ss[1] + ss[2] + ss[3];
    float Qe = qq[0] + qq[1] + qq[2] + qq[3];
    float mean = Se * INV_EDGE_CNT;
    float var  = Qe * INV_EDGE_CNT - mean * mean;
    float sc = rsqrtf(var + EPSBN) * bneg[c];
    ws[WS_ESUM + c] = sc;
    ws[WS_ESQ  + c] = bneb[c] - mean * sc;
  }
  __syncthreads();

  const float* Ux  = ws + WS_UX;
  const float* agg = ws + WS_AGG;

  float v[8];
  float s = 0.f, q = 0.f;
#pragma unroll
  for (int k = 0; k < 8; ++k) {
    int r = tid + 256 * k;
    float t = Ux[(size_t)r * 64 + c] + agg[(size_t)r * 64 + c];
    v[k] = t;
    s += t;
    q = fmaf(t, t, q);
  }
#pragma unroll
  for (int m = 1; m < 64; m <<= 1) {
    s += __shfl_xor(s, m);
    q += __shfl_xor(q, m);
  }
  if ((tid & 63) == 0) { ss[w] = s; qq[w] = q; }
  __syncthreads();
  float Sn = ss[0] + ss[1] + ss[2] + ss[3];
  float Qn = qq[0] + qq[1] + qq[2] + qq[3];
  float mean = Sn * INV_NODE_CNT;
  float var  = Qn * INV_NODE_CNT - mean * mean;
  float scv = rsqrtf(var + EPSBN) * bnng[c];
  float shv = bnnb[c] - mean * scv;
#pragma unroll
  for (int k = 0; k < 8; ++k) {
    int r = tid + 256 * k;
    float y = fmaf(v[k], scv, shv);
    xOut[(size_t)r * 64 + c] = fmaxf(y, 0.f) + x[(size_t)r * 64 + c];
  }
}

// ---------------------------------------------------------------------------
// Pass C (r8/r14 — best measured, at its BW roofline): register-staged LDS
// pipeline, residual from the staged LDS tile, prefolded edge BN.
__global__ __launch_bounds__(256) void k_edgeC(
    const float* __restrict__ e,
    const float* __restrict__ UeW, const float* __restrict__ Ueb,
    const float* __restrict__ ws, float* __restrict__ eOut)
{
  __shared__ __align__(16) float eL[4 * 2048];
  __shared__ __align__(16) __bf16 wLds[4096];

  const int tid  = threadIdx.x;
  const int lane = tid & 63;
  const int w    = tid >> 6;
  const int bi   = blockIdx.x;
  const int b    = bi >> 8;
  const int r16  = lane & 15;
  const int g    = lane >> 4;
  const int sw   = r16 & 7;

  const float* eTile = e + (size_t)bi * (Nv * Hv);
  float* myBuf = &eL[w * 2048];
  float* oTile = eOut + (size_t)bi * (Nv * Hv);

#pragma unroll
  for (int k = 0; k < 2; ++k) {
    const int m = tid * 2 + k;
    const int c = m >> 3, p = m & 7;
    float4 lo = ld4(UeW + (size_t)c * 64 + p * 8);
    float4 hi = ld4(UeW + (size_t)c * 64 + p * 8 + 4);
    *(bf16x8*)(&wLds[(size_t)c * 64 + (size_t)(p ^ (c & 7)) * 8]) = cvt8(lo, hi);
  }

  const float* VXEP = ws + WS_VXE;
  const int jti = (bi >> 4) & 15, r16i = bi & 15;
  float4 ueb4[4], vxei4[4], sc4[4], sh4[4];
#pragma unroll
  for (int t = 0; t < 4; ++t) {
    ueb4[t]  = ld4(Ueb + t * 16 + 4 * g);
    vxei4[t] = ld4(VXEP + ((size_t)((b * 16 + jti) * 4 + t)) * 256 + (g * 16 + r16i) * 4);
    sc4[t]   = ld4(ws + WS_ESUM + t * 16 + 4 * g);
    sh4[t]   = ld4(ws + WS_ESQ  + t * 16 + 4 * g);
  }

  float4 Ga[4], Gb[4];
  float4 Pj[2][4];
  load_tile_G(eTile, w, lane, 0, Ga);
  load_tile_G(eTile, w, lane, 1, Gb);
  {
    const size_t pb0 = (size_t)((b * 16 + (w * 4 + 0)) * 4);
#pragma unroll
    for (int t = 0; t < 4; ++t)
      Pj[0][t] = ld4(VXEP + (pb0 + t) * 256 + lane * 4);
  }
  __syncthreads();
  write_tile_L(myBuf, lane, 0, Ga);
  write_tile_L(myBuf, lane, 1, Gb);

#pragma unroll
  for (int p = 0; p < 4; ++p) {
    bf16x8 wF0[4], wF1[4];
#pragma unroll
    for (int t = 0; t < 4; ++t) {
      const int wr = (16 * t + r16) * 64;
      wF0[t] = *(const bf16x8*)(&wLds[wr + ((g ^ sw) << 3)]);
      wF1[t] = *(const bf16x8*)(&wLds[wr + (((4 + g) ^ sw) << 3)]);
    }
    const float* rbase = myBuf + (p & 1) * 1024 + r16 * 64;
    float4 f0 = ld4(rbase + (((2 * g)     ^ sw) << 2));
    float4 f1 = ld4(rbase + (((2 * g + 1) ^ sw) << 2));
    float4 f2 = ld4(rbase + ((((2 * g)     ^ sw) + 8) << 2));
    float4 f3 = ld4(rbase + ((((2 * g + 1) ^ sw) + 8) << 2));
    bf16x8 aF0 = cvt8(f0, f1);
    bf16x8 aF1 = cvt8(f2, f3);
    float4 res4[4];
#pragma unroll
    for (int t = 0; t < 4; ++t)
      res4[t] = ld4(rbase + (((4 * t + g) ^ sw) << 2));

    if (p < 3) {
      const size_t pbn = (size_t)((b * 16 + (w * 4 + p + 1)) * 4);
#pragma unroll
      for (int t = 0; t < 4; ++t)
        Pj[(p + 1) & 1][t] = ld4(VXEP + (pbn + t) * 256 + lane * 4);
    }
    if (p < 2) load_tile_G(eTile, w, lane, p + 2, (p & 1) ? Gb : Ga);

    f32x4 acc[4];
#pragma unroll
    for (int t = 0; t < 4; ++t) {
      f32x4 z = {0.f, 0.f, 0.f, 0.f};
      acc[t] = __builtin_amdgcn_mfma_f32_16x16x32_bf16(wF0[t], aF0, z, 0, 0, 0);
      acc[t] = __builtin_amdgcn_mfma_f32_16x16x32_bf16(wF1[t], aF1, acc[t], 0, 0, 0);
    }

    const int j = w * 64 + p * 16 + r16;
#pragma unroll
    for (int t = 0; t < 4; ++t) {
      float vj[4] = {Pj[p & 1][t].x, Pj[p & 1][t].y, Pj[p & 1][t].z, Pj[p & 1][t].w};
      float rs[4] = {res4[t].x, res4[t].y, res4[t].z, res4[t].w};
      float ub[4] = {ueb4[t].x, ueb4[t].y, ueb4[t].z, ueb4[t].w};
      float vi[4] = {vxei4[t].x, vxei4[t].y, vxei4[t].z, vxei4[t].w};
      float sc[4] = {sc4[t].x, sc4[t].y, sc4[t].z, sc4[t].w};
      float sh[4] = {sh4[t].x, sh4[t].y, sh4[t].z, sh4[t].w};
      float out[4];
#pragma unroll
      for (int r = 0; r < 4; ++r) {
        float tv = acc[t][r] + ub[r] + vi[r] + vj[r];
        float y  = fmaf(tv, sc[r], sh[r]);
        out[r] = fmaxf(y, 0.f) + rs[r];
      }
      *(float4*)(oTile + (size_t)j * 64 + t * 16 + 4 * g) =
          make_float4(out[0], out[1], out[2], out[3]);
    }

    if (p < 2) write_tile_L(myBuf, lane, p & 1, (p & 1) ? Gb : Ga);
    __builtin_amdgcn_sched_barrier(0);
  }
}

// ---------------------------------------------------------------------------
extern "C" void kernel_launch(void* const* d_in, const int* in_sizes, int n_in,
                              void* d_out, int out_size, void* d_ws, size_t ws_size,
                              hipStream_t stream)
{
  const float* x    = (const float*)d_in[0];
  const float* e    = (const float*)d_in[1];
  const float* UeW  = (const float*)d_in[2];
  const float* Ueb  = (const float*)d_in[3];
  const float* VeW  = (const float*)d_in[4];
  const float* Veb  = (const float*)d_in[5];
  const float* UnW  = (const float*)d_in[6];
  const float* Unb  = (const float*)d_in[7];
  const float* VnW  = (const float*)d_in[8];
  const float* Vnb  = (const float*)d_in[9];
  const float* bneg = (const float*)d_in[10];
  const float* bneb = (const float*)d_in[11];
  const float* bnng = (const float*)d_in[12];
  const float* bnnb = (const float*)d_in[13];

  float* ws   = (float*)d_ws;
  float* xOut = (float*)d_out;
  float* eOut = (float*)d_out + (size_t)ROWS * Hv;

  k_lin<<<256, 128, 0, stream>>>(x, VeW, Veb, UnW, Unb, VnW, Vnb, ws);
  k_edgeA<<<ROWS, 256, 0, stream>>>(e, UeW, Ueb, ws);
  k_node<<<Hv, 256, 0, stream>>>(x, bnng, bnnb, bneg, bneb, ws, xOut);
  k_edgeC<<<ROWS, 256, 0, stream>>>(e, UeW, Ueb, ws, eOut);
}

// Round 20
// 108.921 us; speedup vs baseline: 1.7708x; 1.0123x over previous
//
#include <hip/hip_runtime.h>
#include <cstddef>
#include <cstdint>

// Problem constants (B,N,H) = (8,256,64)
constexpr int Bv = 8, Nv = 256, Hv = 64;
constexpr int ROWS = Bv * Nv;            // 2048
constexpr float INV_EDGE_CNT = 1.0f / (8.0f * 256.0f * 256.0f);
constexpr float INV_NODE_CNT = 1.0f / 2048.0f;
constexpr float EPSBN = 1e-5f;

// ws layout (float units)
constexpr size_t WS_VXEB = 0;        // bf16[2048*64]: ((tile*2+plane)*64+slot)*8+4*half
constexpr size_t WS_VXNB = 65536;    // bf16[2048*64] same layout
constexpr size_t WS_UX   = 131072;   // f32 [2048][64] linear
constexpr size_t WS_AGG  = 262144;   // f32 [2048][64] linear
constexpr size_t WS_ESUM = 393216;   // [64] k_node writes edge-BN scale
constexpr size_t WS_ESQ  = 393280;   // [64] k_node writes edge-BN shift
constexpr size_t WS_PART = 393344;   // f32 [2048][128] per-block partial s|q

typedef __bf16 bf16x8 __attribute__((ext_vector_type(8)));
typedef __bf16 bf16x4 __attribute__((ext_vector_type(4)));
typedef float  f32x4  __attribute__((ext_vector_type(4)));

__device__ __forceinline__ float4 ld4(const float* p) {
  return *reinterpret_cast<const float4*>(p);
}

__device__ __forceinline__ bf16x8 cvt8(float4 a, float4 b) {
  bf16x8 r;
  r[0] = (__bf16)a.x; r[1] = (__bf16)a.y; r[2] = (__bf16)a.z; r[3] = (__bf16)a.w;
  r[4] = (__bf16)b.x; r[5] = (__bf16)b.y; r[6] = (__bf16)b.z; r[7] = (__bf16)b.w;
  return r;
}

// Staging helpers: global tile -> regs with fully-coalesced lane-consecutive
// 16B loads (chunk-swizzled source), then linear LDS write.
__device__ __forceinline__ void load_tile_G(const float* eTile, int w, int lane,
                                            int tt, float4 G[4]) {
#pragma unroll
  for (int k = 0; k < 4; ++k) {
    const int m  = k * 64 + lane;
    const int rl = m >> 4;
    const int pp = m & 15;
    const int cc = pp ^ (rl & 7);
    G[k] = ld4(eTile + (size_t)(w * 64 + tt * 16 + rl) * 64 + cc * 4);
  }
}

__device__ __forceinline__ void write_tile_L(float* myBuf, int lane, int s,
                                             const float4 G[4]) {
#pragma unroll
  for (int k = 0; k < 4; ++k)
    *(float4*)(myBuf + s * 1024 + k * 256 + lane * 4) = G[k];
}

#define DOT4(acc, a, b) \
  acc = fmaf((a).x, (b).x, fmaf((a).y, (b).y, fmaf((a).z, (b).z, fmaf((a).w, (b).w, acc))))

// ---------------------------------------------------------------------------
// Linears: Vxe / Vxn packed bf16 (2-plane lane-linear layout, halves edge
// epilogue L2 traffic; numerics validated r12); Ux f32 linear.
__global__ __launch_bounds__(128) void k_lin(
    const float* __restrict__ x,
    const float* __restrict__ VeW, const float* __restrict__ Veb,
    const float* __restrict__ UnW, const float* __restrict__ Unb,
    const float* __restrict__ VnW, const float* __restrict__ Vnb,
    float* __restrict__ ws)
{
  const int idx = blockIdx.x * 128 + threadIdx.x;   // 32768 total
  const int r  = idx >> 4;           // row 0..2047
  const int tg = idx & 15;
  const int t  = tg >> 2, g = tg & 3;
  const int c0 = t * 16 + g * 4;

  const float4* x4 = (const float4*)(x + (size_t)r * 64);
  float a1[4] = {}, a2[4] = {}, a3[4] = {};
#pragma unroll
  for (int h = 0; h < 16; ++h) {
    float4 xv = x4[h];
#pragma unroll
    for (int cc = 0; cc < 4; ++cc) {
      float4 w1 = ld4(VeW + (size_t)(c0 + cc) * 64 + h * 4); DOT4(a1[cc], xv, w1);
      float4 w2 = ld4(UnW + (size_t)(c0 + cc) * 64 + h * 4); DOT4(a2[cc], xv, w2);
      float4 w3 = ld4(VnW + (size_t)(c0 + cc) * 64 + h * 4); DOT4(a3[cc], xv, w3);
    }
  }

  const int b = r >> 8, jt = (r >> 4) & 15, r16 = r & 15;
  const int laneSlot = 16 * g + r16;
  const size_t eb = (((size_t)(b * 16 + jt) * 2 + (t >> 1)) * 64 + laneSlot) * 8
                    + 4 * (t & 1);
  __bf16* vxeb = (__bf16*)(ws + WS_VXEB);
  __bf16* vxnb = (__bf16*)(ws + WS_VXNB);
  bf16x4 ve, vn;
#pragma unroll
  for (int cc = 0; cc < 4; ++cc) {
    ve[cc] = (__bf16)(a1[cc] + Veb[c0 + cc]);
    vn[cc] = (__bf16)(a3[cc] + Vnb[c0 + cc]);
  }
  *(bf16x4*)(&vxeb[eb]) = ve;
  *(bf16x4*)(&vxnb[eb]) = vn;
  *(float4*)(&ws[WS_UX + (size_t)r * 64 + c0]) =
      make_float4(a2[0] + Unb[c0], a2[1] + Unb[c0 + 1], a2[2] + Unb[c0 + 2], a2[3] + Unb[c0 + 3]);
}

// ---------------------------------------------------------------------------
// Pass A (r19 skeleton + bf16 packed panels): W->LDS once; e staged via
// coalesced reg->LDS pipeline; vj/vn double-buffered bf16x8 one phase ahead;
// sigmoid/stats epilogue; reduce tail through the idle staging LDS.
__global__ __launch_bounds__(256) void k_edgeA(
    const float* __restrict__ e,
    const float* __restrict__ UeW, const float* __restrict__ Ueb,
    float* __restrict__ ws)
{
  __shared__ __align__(16) float eL[4 * 2048];     // 32KB tiles (+reduce reuse)
  __shared__ __align__(16) __bf16 wLds[4096];      // 8KB W, chunk-swizzled

  const int tid  = threadIdx.x;
  const int lane = tid & 63;
  const int w    = tid >> 6;
  const int bi   = blockIdx.x;
  const int b    = bi >> 8;
  const int r16  = lane & 15;
  const int g    = lane >> 4;
  const int sw   = r16 & 7;

  const float* eTile = e + (size_t)bi * (Nv * Hv);
  float* myBuf = &eL[w * 2048];

  // stage W -> LDS (bf16, chunk p of row c stored at p ^ (c&7)), coalesced
#pragma unroll
  for (int k = 0; k < 2; ++k) {
    const int m = tid * 2 + k;
    const int c = m >> 3, p = m & 7;
    float4 lo = ld4(UeW + (size_t)c * 64 + p * 8);
    float4 hi = ld4(UeW + (size_t)c * 64 + p * 8 + 4);
    *(bf16x8*)(&wLds[(size_t)c * 64 + (size_t)(p ^ (c & 7)) * 8]) = cvt8(lo, hi);
  }

  const __bf16* vxeb = (const __bf16*)(ws + WS_VXEB);
  const __bf16* vxnb = (const __bf16*)(ws + WS_VXNB);

  // uv = Ueb + Vxe_i (bf16 planes; slot = 16g + r16i)
  const int jti = (bi >> 4) & 15, r16i = bi & 15;
  const int li  = 16 * g + r16i;
  bf16x8 veiL = *(const bf16x8*)(&vxeb[(((size_t)(b * 16 + jti) * 2 + 0) * 64 + li) * 8]);
  bf16x8 veiH = *(const bf16x8*)(&vxeb[(((size_t)(b * 16 + jti) * 2 + 1) * 64 + li) * 8]);
  float uv[4][4];
#pragma unroll
  for (int t = 0; t < 4; ++t) {
    float4 ub = ld4(Ueb + t * 16 + 4 * g);
    float u[4] = {ub.x, ub.y, ub.z, ub.w};
#pragma unroll
    for (int r = 0; r < 4; ++r) {
      float vei = (t < 2) ? (float)veiL[4 * t + r] : (float)veiH[4 * (t - 2) + r];
      uv[t][r] = u[r] + vei;
    }
  }

  // prologue: tiles 0,1 -> regs; packed phase-0 panels in flight
  float4 Ga[4], Gb[4];
  bf16x8 PjL[2], PjH[2], PnL[2], PnH[2];
  load_tile_G(eTile, w, lane, 0, Ga);
  load_tile_G(eTile, w, lane, 1, Gb);
  {
    const size_t pb = ((size_t)(b * 16 + w * 4) * 2) * 64 + lane;
    PjL[0] = *(const bf16x8*)(&vxeb[pb * 8]);
    PjH[0] = *(const bf16x8*)(&vxeb[(pb + 64) * 8]);
    PnL[0] = *(const bf16x8*)(&vxnb[pb * 8]);
    PnH[0] = *(const bf16x8*)(&vxnb[(pb + 64) * 8]);
  }
  __syncthreads();                       // wLds ready
  write_tile_L(myBuf, lane, 0, Ga);
  write_tile_L(myBuf, lane, 1, Gb);

  // W fragments from LDS once
  bf16x8 wF0[4], wF1[4];
#pragma unroll
  for (int t = 0; t < 4; ++t) {
    const int wr = (16 * t + r16) * 64;
    wF0[t] = *(const bf16x8*)(&wLds[wr + ((g ^ sw) << 3)]);
    wF1[t] = *(const bf16x8*)(&wLds[wr + (((4 + g) ^ sw) << 3)]);
  }

  float sS[4][4] = {}, sQ[4][4] = {}, sA[4][4] = {};

#pragma unroll
  for (int p = 0; p < 4; ++p) {
    const float* rbase = myBuf + (p & 1) * 1024 + r16 * 64;
    float4 f0 = ld4(rbase + (((2 * g)     ^ sw) << 2));
    float4 f1 = ld4(rbase + (((2 * g + 1) ^ sw) << 2));
    float4 f2 = ld4(rbase + ((((2 * g)     ^ sw) + 8) << 2));
    float4 f3 = ld4(rbase + ((((2 * g + 1) ^ sw) + 8) << 2));
    bf16x8 aF0 = cvt8(f0, f1);
    bf16x8 aF1 = cvt8(f2, f3);

    // prefetch: packed panel for p+1, tile p+2 (full phase in flight)
    if (p < 3) {
      const size_t pbn = ((size_t)(b * 16 + w * 4 + p + 1) * 2) * 64 + lane;
      PjL[(p + 1) & 1] = *(const bf16x8*)(&vxeb[pbn * 8]);
      PjH[(p + 1) & 1] = *(const bf16x8*)(&vxeb[(pbn + 64) * 8]);
      PnL[(p + 1) & 1] = *(const bf16x8*)(&vxnb[pbn * 8]);
      PnH[(p + 1) & 1] = *(const bf16x8*)(&vxnb[(pbn + 64) * 8]);
    }
    if (p < 2) load_tile_G(eTile, w, lane, p + 2, (p & 1) ? Gb : Ga);

    f32x4 acc[4];
#pragma unroll
    for (int t = 0; t < 4; ++t) {
      f32x4 z = {0.f, 0.f, 0.f, 0.f};
      acc[t] = __builtin_amdgcn_mfma_f32_16x16x32_bf16(wF0[t], aF0, z, 0, 0, 0);
      acc[t] = __builtin_amdgcn_mfma_f32_16x16x32_bf16(wF1[t], aF1, acc[t], 0, 0, 0);
    }

#pragma unroll
    for (int t = 0; t < 4; ++t) {
#pragma unroll
      for (int r = 0; r < 4; ++r) {
        float vj = (t < 2) ? (float)PjL[p & 1][4 * t + r] : (float)PjH[p & 1][4 * (t - 2) + r];
        float vn = (t < 2) ? (float)PnL[p & 1][4 * t + r] : (float)PnH[p & 1][4 * (t - 2) + r];
        float tv = acc[t][r] + uv[t][r] + vj;
        sS[t][r] += tv;
        sQ[t][r]  = fmaf(tv, tv, sQ[t][r]);
        float sg  = __builtin_amdgcn_rcpf(1.0f + __expf(-tv));
        sA[t][r]  = fmaf(sg, vn, sA[t][r]);
      }
    }

    // write tile p+2 into the buffer just consumed (in-order LDS per wave)
    if (p < 2) write_tile_L(myBuf, lane, p & 1, (p & 1) ? Gb : Ga);
    __builtin_amdgcn_sched_barrier(0);
  }

  // reduce over the 16 j-lanes (bits 0..3 of lane)
#pragma unroll
  for (int t = 0; t < 4; ++t)
#pragma unroll
    for (int r = 0; r < 4; ++r) {
#pragma unroll
      for (int m = 1; m < 16; m <<= 1) {
        sS[t][r] += __shfl_xor(sS[t][r], m);
        sQ[t][r] += __shfl_xor(sQ[t][r], m);
        sA[t][r] += __shfl_xor(sA[t][r], m);
      }
    }

  // per-wave partials into the wave's own (now idle) staging region
  if (r16 == 0) {
#pragma unroll
    for (int t = 0; t < 4; ++t) {
      const int cb = t * 16 + 4 * g;
      *(float4*)(&myBuf[cb])       = make_float4(sA[t][0], sA[t][1], sA[t][2], sA[t][3]);
      *(float4*)(&myBuf[256 + cb]) = make_float4(sS[t][0], sS[t][1], sS[t][2], sS[t][3]);
      *(float4*)(&myBuf[512 + cb]) = make_float4(sQ[t][0], sQ[t][1], sQ[t][2], sQ[t][3]);
    }
  }
  __syncthreads();
  if (tid < 64) {
    const int c = tid;
    float a  = eL[c]       + eL[2048 + c]       + eL[4096 + c]       + eL[6144 + c];
    ws[WS_AGG + (size_t)bi * 64 + c] = a;
    float s  = eL[256 + c] + eL[2048 + 256 + c] + eL[4096 + 256 + c] + eL[6144 + 256 + c];
    float qv = eL[512 + c] + eL[2048 + 512 + c] + eL[4096 + 512 + c] + eL[6144 + 512 + c];
    ws[WS_PART + (size_t)bi * 128 + c]      = s;     // no atomics
    ws[WS_PART + (size_t)bi * 128 + 64 + c] = qv;
  }
}

// ---------------------------------------------------------------------------
// Node path: reduce edge partials -> fold edge-BN scale/shift; then
// x_tmp = Ux + agg ; BN over (B,N) ; relu + residual.
__global__ __launch_bounds__(256) void k_node(
    const float* __restrict__ x,
    const float* __restrict__ bnng, const float* __restrict__ bnnb,
    const float* __restrict__ bneg, const float* __restrict__ bneb,
    float* __restrict__ ws, float* __restrict__ xOut)
{
  const int c = blockIdx.x;
  const int tid = threadIdx.x;
  __shared__ float ss[4], qq[4];
  const int w = tid >> 6;

  float S = 0.f, Q = 0.f;
#pragma unroll
  for (int k = 0; k < 8; ++k) {
    const size_t row = (size_t)(tid + 256 * k) * 128;
    S += ws[WS_PART + row + c];
    Q += ws[WS_PART + row + 64 + c];
  }
#pragma unroll
  for (int m = 1; m < 64; m <<= 1) {
    S += __shfl_xor(S, m);
    Q += __shfl_xor(Q, m);
  }
  if ((tid & 63) == 0) { ss[w] = S; qq[w] = Q; }
  __syncthreads();
  if (tid == 0) {
    float Se = ss[0] + ss[1] + ss[2] + ss[3];
    float Qe = qq[0] + qq[1] + qq[2] + qq[3];
    float mean = Se * INV_EDGE_CNT;
    float var  = Qe * INV_EDGE_CNT - mean * mean;
    float sc = rsqrtf(var + EPSBN) * bneg[c];
    ws[WS_ESUM + c] = sc;
    ws[WS_ESQ  + c] = bneb[c] - mean * sc;
  }
  __syncthreads();

  const float* Ux  = ws + WS_UX;
  const float* agg = ws + WS_AGG;

  float v[8];
  float s = 0.f, q = 0.f;
#pragma unroll
  for (int k = 0; k < 8; ++k) {
    int r = tid + 256 * k;
    float t = Ux[(size_t)r * 64 + c] + agg[(size_t)r * 64 + c];
    v[k] = t;
    s += t;
    q = fmaf(t, t, q);
  }
#pragma unroll
  for (int m = 1; m < 64; m <<= 1) {
    s += __shfl_xor(s, m);
    q += __shfl_xor(q, m);
  }
  if ((tid & 63) == 0) { ss[w] = s; qq[w] = q; }
  __syncthreads();
  float Sn = ss[0] + ss[1] + ss[2] + ss[3];
  float Qn = qq[0] + qq[1] + qq[2] + qq[3];
  float mean = Sn * INV_NODE_CNT;
  float var  = Qn * INV_NODE_CNT - mean * mean;
  float scv = rsqrtf(var + EPSBN) * bnng[c];
  float shv = bnnb[c] - mean * scv;
#pragma unroll
  for (int k = 0; k < 8; ++k) {
    int r = tid + 256 * k;
    float y = fmaf(v[k], scv, shv);
    xOut[(size_t)r * 64 + c] = fmaxf(y, 0.f) + x[(size_t)r * 64 + c];
  }
}

// ---------------------------------------------------------------------------
// Pass C (r19 skeleton + bf16 packed Pj): register-staged LDS pipeline,
// residual from the staged LDS tile, prefolded edge BN.
__global__ __launch_bounds__(256) void k_edgeC(
    const float* __restrict__ e,
    const float* __restrict__ UeW, const float* __restrict__ Ueb,
    const float* __restrict__ ws, float* __restrict__ eOut)
{
  __shared__ __align__(16) float eL[4 * 2048];
  __shared__ __align__(16) __bf16 wLds[4096];

  const int tid  = threadIdx.x;
  const int lane = tid & 63;
  const int w    = tid >> 6;
  const int bi   = blockIdx.x;
  const int b    = bi >> 8;
  const int r16  = lane & 15;
  const int g    = lane >> 4;
  const int sw   = r16 & 7;

  const float* eTile = e + (size_t)bi * (Nv * Hv);
  float* myBuf = &eL[w * 2048];
  float* oTile = eOut + (size_t)bi * (Nv * Hv);

#pragma unroll
  for (int k = 0; k < 2; ++k) {
    const int m = tid * 2 + k;
    const int c = m >> 3, p = m & 7;
    float4 lo = ld4(UeW + (size_t)c * 64 + p * 8);
    float4 hi = ld4(UeW + (size_t)c * 64 + p * 8 + 4);
    *(bf16x8*)(&wLds[(size_t)c * 64 + (size_t)(p ^ (c & 7)) * 8]) = cvt8(lo, hi);
  }

  const __bf16* vxeb = (const __bf16*)(ws + WS_VXEB);
  const int jti = (bi >> 4) & 15, r16i = bi & 15;
  const int li  = 16 * g + r16i;
  bf16x8 veiL = *(const bf16x8*)(&vxeb[(((size_t)(b * 16 + jti) * 2 + 0) * 64 + li) * 8]);
  bf16x8 veiH = *(const bf16x8*)(&vxeb[(((size_t)(b * 16 + jti) * 2 + 1) * 64 + li) * 8]);
  float uv[4][4];
  float4 sc4[4], sh4[4];
#pragma unroll
  for (int t = 0; t < 4; ++t) {
    float4 ub = ld4(Ueb + t * 16 + 4 * g);
    float u[4] = {ub.x, ub.y, ub.z, ub.w};
#pragma unroll
    for (int r = 0; r < 4; ++r) {
      float vei = (t < 2) ? (float)veiL[4 * t + r] : (float)veiH[4 * (t - 2) + r];
      uv[t][r] = u[r] + vei;
    }
    sc4[t] = ld4(ws + WS_ESUM + t * 16 + 4 * g);
    sh4[t] = ld4(ws + WS_ESQ  + t * 16 + 4 * g);
  }

  float4 Ga[4], Gb[4];
  bf16x8 PjL[2], PjH[2];
  load_tile_G(eTile, w, lane, 0, Ga);
  load_tile_G(eTile, w, lane, 1, Gb);
  {
    const size_t pb = ((size_t)(b * 16 + w * 4) * 2) * 64 + lane;
    PjL[0] = *(const bf16x8*)(&vxeb[pb * 8]);
    PjH[0] = *(const bf16x8*)(&vxeb[(pb + 64) * 8]);
  }
  __syncthreads();
  write_tile_L(myBuf, lane, 0, Ga);
  write_tile_L(myBuf, lane, 1, Gb);

#pragma unroll
  for (int p = 0; p < 4; ++p) {
    bf16x8 wF0[4], wF1[4];
#pragma unroll
    for (int t = 0; t < 4; ++t) {
      const int wr = (16 * t + r16) * 64;
      wF0[t] = *(const bf16x8*)(&wLds[wr + ((g ^ sw) << 3)]);
      wF1[t] = *(const bf16x8*)(&wLds[wr + (((4 + g) ^ sw) << 3)]);
    }
    const float* rbase = myBuf + (p & 1) * 1024 + r16 * 64;
    float4 f0 = ld4(rbase + (((2 * g)     ^ sw) << 2));
    float4 f1 = ld4(rbase + (((2 * g + 1) ^ sw) << 2));
    float4 f2 = ld4(rbase + ((((2 * g)     ^ sw) + 8) << 2));
    float4 f3 = ld4(rbase + ((((2 * g + 1) ^ sw) + 8) << 2));
    bf16x8 aF0 = cvt8(f0, f1);
    bf16x8 aF1 = cvt8(f2, f3);
    float4 res4[4];
#pragma unroll
    for (int t = 0; t < 4; ++t)
      res4[t] = ld4(rbase + (((4 * t + g) ^ sw) << 2));

    if (p < 3) {
      const size_t pbn = ((size_t)(b * 16 + w * 4 + p + 1) * 2) * 64 + lane;
      PjL[(p + 1) & 1] = *(const bf16x8*)(&vxeb[pbn * 8]);
      PjH[(p + 1) & 1] = *(const bf16x8*)(&vxeb[(pbn + 64) * 8]);
    }
    if (p < 2) load_tile_G(eTile, w, lane, p + 2, (p & 1) ? Gb : Ga);

    f32x4 acc[4];
#pragma unroll
    for (int t = 0; t < 4; ++t) {
      f32x4 z = {0.f, 0.f, 0.f, 0.f};
      acc[t] = __builtin_amdgcn_mfma_f32_16x16x32_bf16(wF0[t], aF0, z, 0, 0, 0);
      acc[t] = __builtin_amdgcn_mfma_f32_16x16x32_bf16(wF1[t], aF1, acc[t], 0, 0, 0);
    }

    const int j = w * 64 + p * 16 + r16;
#pragma unroll
    for (int t = 0; t < 4; ++t) {
      float rs[4] = {res4[t].x, res4[t].y, res4[t].z, res4[t].w};
      float sc[4] = {sc4[t].x, sc4[t].y, sc4[t].z, sc4[t].w};
      float sh[4] = {sh4[t].x, sh4[t].y, sh4[t].z, sh4[t].w};
      float out[4];
#pragma unroll
      for (int r = 0; r < 4; ++r) {
        float vj = (t < 2) ? (float)PjL[p & 1][4 * t + r] : (float)PjH[p & 1][4 * (t - 2) + r];
        float tv = acc[t][r] + uv[t][r] + vj;
        float y  = fmaf(tv, sc[r], sh[r]);
        out[r] = fmaxf(y, 0.f) + rs[r];
      }
      *(float4*)(oTile + (size_t)j * 64 + t * 16 + 4 * g) =
          make_float4(out[0], out[1], out[2], out[3]);
    }

    if (p < 2) write_tile_L(myBuf, lane, p & 1, (p & 1) ? Gb : Ga);
    __builtin_amdgcn_sched_barrier(0);
  }
}

// ---------------------------------------------------------------------------
extern "C" void kernel_launch(void* const* d_in, const int* in_sizes, int n_in,
                              void* d_out, int out_size, void* d_ws, size_t ws_size,
                              hipStream_t stream)
{
  const float* x    = (const float*)d_in[0];
  const float* e    = (const float*)d_in[1];
  const float* UeW  = (const float*)d_in[2];
  const float* Ueb  = (const float*)d_in[3];
  const float* VeW  = (const float*)d_in[4];
  const float* Veb  = (const float*)d_in[5];
  const float* UnW  = (const float*)d_in[6];
  const float* Unb  = (const float*)d_in[7];
  const float* VnW  = (const float*)d_in[8];
  const float* Vnb  = (const float*)d_in[9];
  const float* bneg = (const float*)d_in[10];
  const float* bneb = (const float*)d_in[11];
  const float* bnng = (const float*)d_in[12];
  const float* bnnb = (const float*)d_in[13];

  float* ws   = (float*)d_ws;
  float* xOut = (float*)d_out;
  float* eOut = (float*)d_out + (size_t)ROWS * Hv;

  k_lin<<<256, 128, 0, stream>>>(x, VeW, Veb, UnW, Unb, VnW, Vnb, ws);
  k_edgeA<<<ROWS, 256, 0, stream>>>(e, UeW, Ueb, ws);
  k_node<<<Hv, 256, 0, stream>>>(x, bnng, bnnb, bneg, bneb, ws, xOut);
  k_edgeC<<<ROWS, 256, 0, stream>>>(e, UeW, Ueb, ws, eOut);
}